// Round 1
// baseline (167.187 us; speedup 1.0000x reference)
//
#include <hip/hip_runtime.h>
#include <stdint.h>

typedef unsigned short u16;
typedef short bf16x8 __attribute__((ext_vector_type(8)));
typedef unsigned short u16x8 __attribute__((ext_vector_type(8)));
typedef unsigned short u16x4 __attribute__((ext_vector_type(4)));
typedef float f32x4 __attribute__((ext_vector_type(4)));

#define S_ 2048
#define DM 512
#define DH 64
#define CL 64           // chunk length
#define NCH 32          // chunks per sequence = 2048/64

__device__ __forceinline__ float b2f(u16 u) { return __uint_as_float(((unsigned)u) << 16); }
__device__ __forceinline__ u16 f2b(float f) {
    unsigned v = __float_as_uint(f);
    unsigned r = v + 0x7fffu + ((v >> 16) & 1u);
    return (u16)(r >> 16);
}
__device__ __forceinline__ float phi_elu(float x) { return x > 0.f ? x + 1.f : __expf(x); }
__device__ __forceinline__ float clip01(float v) { return fminf(fmaxf(v, 0.01f), 0.995f); }

// ---------------- RMSNorm: h = x * rsqrt(mean(x^2)+1e-5) * ln_w  (bf16 out) ----------
__global__ __launch_bounds__(256) void k_rmsnorm(const float* __restrict__ x,
                                                 const float* __restrict__ lnw,
                                                 u16* __restrict__ h) {
    int wave = threadIdx.x >> 6, lane = threadIdx.x & 63;
    int row = blockIdx.x * 4 + wave;
    const float* xr = x + (size_t)row * DM + lane * 8;
    float4 v0 = *(const float4*)xr;
    float4 v1 = *(const float4*)(xr + 4);
    float ss = v0.x * v0.x + v0.y * v0.y + v0.z * v0.z + v0.w * v0.w +
               v1.x * v1.x + v1.y * v1.y + v1.z * v1.z + v1.w * v1.w;
    #pragma unroll
    for (int off = 32; off; off >>= 1) ss += __shfl_xor(ss, off, 64);
    float sc = rsqrtf(ss * (1.f / DM) + 1e-5f);
    const float* wr_ = lnw + lane * 8;
    float4 w0 = *(const float4*)wr_;
    float4 w1 = *(const float4*)(wr_ + 4);
    u16x8 o;
    o[0] = f2b(v0.x * sc * w0.x); o[1] = f2b(v0.y * sc * w0.y);
    o[2] = f2b(v0.z * sc * w0.z); o[3] = f2b(v0.w * sc * w0.w);
    o[4] = f2b(v1.x * sc * w1.x); o[5] = f2b(v1.y * sc * w1.y);
    o[6] = f2b(v1.z * sc * w1.z); o[7] = f2b(v1.w * sc * w1.w);
    *(u16x8*)(h + (size_t)row * DM + lane * 8) = o;
}

// ---------------- convert weights to bf16: wcat = [Wq;Wk;Wv] (1536x512), wo (512x512) --
__global__ __launch_bounds__(256) void k_convw(const float* __restrict__ Wq, const float* __restrict__ Wk,
                                               const float* __restrict__ Wv, const float* __restrict__ Wo,
                                               u16* __restrict__ wcat, u16* __restrict__ wo) {
    int idx = blockIdx.x * 256 + threadIdx.x;   // 0..262143
    int e0 = idx << 2;
    if (e0 < 1536 * 512) {
        int r = e0 >> 9, ccol = e0 & 511;
        const float* src = (r < 512) ? (Wq + (size_t)r * 512)
                         : (r < 1024) ? (Wk + (size_t)(r - 512) * 512)
                                      : (Wv + (size_t)(r - 1024) * 512);
        float4 v = *(const float4*)(src + ccol);
        u16x4 o = {f2b(v.x), f2b(v.y), f2b(v.z), f2b(v.w)};
        *(u16x4*)(wcat + e0) = o;
    } else {
        int e = e0 - 1536 * 512;
        float4 v = *(const float4*)(Wo + e);
        u16x4 o = {f2b(v.x), f2b(v.y), f2b(v.z), f2b(v.w)};
        *(u16x4*)(wo + e) = o;
    }
}

// ---------------- MFMA bf16 GEMM: C[M,N] = A[M,K] @ B[N,K]^T, 128x128 tile ------------
// MODE 0: epilogue -> phi/mask, scatter to head-layout qh/kh/vh (bf16)
// MODE 1: epilogue -> out = acc + x + bo (f32)
template<int MODE>
__global__ __launch_bounds__(256) void k_gemm(const u16* __restrict__ A, const u16* __restrict__ Bw, int K,
                                              const float* __restrict__ mask, u16* __restrict__ qh,
                                              u16* __restrict__ kh, u16* __restrict__ vh,
                                              const float* __restrict__ xres, const float* __restrict__ bo,
                                              float* __restrict__ outp) {
    __shared__ u16 As[128 * 40];
    __shared__ u16 Bs[128 * 40];
    int tid = threadIdx.x;
    int lane = tid & 63, wave = tid >> 6;
    int wr = wave >> 1, wc = wave & 1;
    int m0 = blockIdx.x * 128, n0 = blockIdx.y * 128;
    f32x4 acc[4][4] = {};
    int srow = tid >> 2, sc8 = (tid & 3) << 3;
    const u16* Ag0 = A + (size_t)(m0 + srow) * K + sc8;
    const u16* Ag1 = Ag0 + (size_t)64 * K;
    const u16* Bg0 = Bw + (size_t)(n0 + srow) * K + sc8;
    const u16* Bg1 = Bg0 + (size_t)64 * K;
    u16* As0 = &As[srow * 40 + sc8];
    u16* As1 = &As[(srow + 64) * 40 + sc8];
    u16* Bs0 = &Bs[srow * 40 + sc8];
    u16* Bs1 = &Bs[(srow + 64) * 40 + sc8];
    int kh8 = (lane >> 4) << 3;
    for (int k0 = 0; k0 < K; k0 += 32) {
        u16x8 a0 = *(const u16x8*)(Ag0 + k0);
        u16x8 a1 = *(const u16x8*)(Ag1 + k0);
        u16x8 b0 = *(const u16x8*)(Bg0 + k0);
        u16x8 b1 = *(const u16x8*)(Bg1 + k0);
        if (k0) __syncthreads();
        *(u16x8*)As0 = a0; *(u16x8*)As1 = a1;
        *(u16x8*)Bs0 = b0; *(u16x8*)Bs1 = b1;
        __syncthreads();
        bf16x8 af[4], bfr[4];
        #pragma unroll
        for (int m = 0; m < 4; m++) af[m] = *(const bf16x8*)&As[(wr * 64 + m * 16 + (lane & 15)) * 40 + kh8];
        #pragma unroll
        for (int n = 0; n < 4; n++) bfr[n] = *(const bf16x8*)&Bs[(wc * 64 + n * 16 + (lane & 15)) * 40 + kh8];
        #pragma unroll
        for (int m = 0; m < 4; m++)
            #pragma unroll
            for (int n = 0; n < 4; n++)
                acc[m][n] = __builtin_amdgcn_mfma_f32_16x16x32_bf16(af[m], bfr[n], acc[m][n], 0, 0, 0);
    }
    #pragma unroll
    for (int m = 0; m < 4; m++) {
        int rbase = m0 + wr * 64 + m * 16 + ((lane >> 4) << 2);
        #pragma unroll
        for (int n = 0; n < 4; n++) {
            int col = n0 + wc * 64 + n * 16 + (lane & 15);
            #pragma unroll
            for (int r = 0; r < 4; r++) {
                int row = rbase + r;
                float v = acc[m][n][r];
                if constexpr (MODE == 0) {
                    int mat = col >> 9, f = col & 511, hh = f >> 6, j = f & 63;
                    int b = row >> 11, s = row & 2047;
                    size_t di = ((size_t)((b << 3) + hh) * S_ + s) * DH + j;
                    if (mat == 0) qh[di] = f2b(phi_elu(v));
                    else if (mat == 1) kh[di] = f2b(phi_elu(v) * mask[(b << 11) + s]);
                    else vh[di] = f2b(v);
                } else {
                    size_t oi = (size_t)row * DM + col;
                    outp[oi] = v + xres[oi] + bo[col];
                }
            }
        }
    }
}

// ---------------- beta + log2 decays per (bh, s) --------------------------------------
__global__ __launch_bounds__(256) void k_beta(const u16* __restrict__ h, const float* __restrict__ Wb,
                                              const float* __restrict__ bb, const float* __restrict__ rec,
                                              const float* __restrict__ bb1p, const float* __restrict__ bb2p,
                                              float* __restrict__ lb1, float* __restrict__ lb2) {
    int wave = threadIdx.x >> 6, lane = threadIdx.x & 63;
    int row = blockIdx.x * 4 + wave;   // 0..8191 == b*2048+s
    const u16* hr = h + (size_t)row * DM + lane * 8;
    u16x8 hu = *(const u16x8*)hr;
    float hv[8];
    #pragma unroll
    for (int j = 0; j < 8; j++) hv[j] = b2f(hu[j]);
    float acc[8];
    #pragma unroll
    for (int hd = 0; hd < 8; hd++) {
        const float* wp = Wb + hd * DM + lane * 8;
        float4 w0 = *(const float4*)wp;
        float4 w1 = *(const float4*)(wp + 4);
        acc[hd] = hv[0] * w0.x + hv[1] * w0.y + hv[2] * w0.z + hv[3] * w0.w +
                  hv[4] * w1.x + hv[5] * w1.y + hv[6] * w1.z + hv[7] * w1.w;
    }
    #pragma unroll
    for (int hd = 0; hd < 8; hd++) {
        #pragma unroll
        for (int off = 32; off; off >>= 1) acc[hd] += __shfl_xor(acc[hd], off, 64);
    }
    if (lane == 0) {
        float b1b = clip01(1.f / (1.f + __expf(-bb1p[0])));
        float b2b = clip01(1.f / (1.f + __expf(-bb2p[0])));
        int b = row >> 11, s = row & 2047;
        #pragma unroll
        for (int hd = 0; hd < 8; hd++) {
            float logit = acc[hd] + bb[hd] + rec[hd];
            float beta = 1.f / (1.f + __expf(-logit));
            float bin = clip01(beta);
            float b1 = clip01(b1b * bin);
            float b2 = clip01(b2b * bin);
            size_t o = (size_t)((b << 3) + hd) * S_ + s;
            lb1[o] = log2f(b1);
            lb2[o] = log2f(b2);
        }
    }
}

// ---------------- pass1: per-chunk local sums S1,S2 (64x64), z1,z2 (64), P1,P2 --------
__global__ __launch_bounds__(256) void k_pass1(const u16* __restrict__ kh, const u16* __restrict__ vh,
                                               const float* __restrict__ lb1, const float* __restrict__ lb2,
                                               float* __restrict__ S1, float* __restrict__ S2,
                                               float* __restrict__ z1, float* __restrict__ z2,
                                               float* __restrict__ P1, float* __restrict__ P2) {
    __shared__ u16 Kt[64 * 72];     // Kt[i][s] = k'[s][i]
    __shared__ float Vs[64 * 72];   // Vs[s][j]
    __shared__ float Ls1[64], Ls2[64], w1s[64], w2s[64];
    int tid = threadIdx.x;
    int bh = blockIdx.x >> 5, c = blockIdx.x & 31;
    int wave = tid >> 6, lane = tid & 63;
    size_t base = ((size_t)bh * S_ + c * CL) * DH;
    if (wave == 0) {
        float v = lb1[(size_t)bh * S_ + c * CL + lane];
        #pragma unroll
        for (int d = 1; d < 64; d <<= 1) { float o = __shfl_up(v, d, 64); if (lane >= d) v += o; }
        Ls1[lane] = v;
    } else if (wave == 1) {
        float v = lb2[(size_t)bh * S_ + c * CL + lane];
        #pragma unroll
        for (int d = 1; d < 64; d <<= 1) { float o = __shfl_up(v, d, 64); if (lane >= d) v += o; }
        Ls2[lane] = v;
    }
    {   // stage
        int s = tid >> 2, i0 = (tid & 3) << 4;
        const u16* kr = kh + base + (size_t)s * DH + i0;
        u16x8 kk0 = *(const u16x8*)kr;
        u16x8 kk1 = *(const u16x8*)(kr + 8);
        #pragma unroll
        for (int q = 0; q < 8; q++) { Kt[(i0 + q) * 72 + s] = kk0[q]; Kt[(i0 + 8 + q) * 72 + s] = kk1[q]; }
        const u16* vr = vh + base + (size_t)s * DH + i0;
        u16x8 vv0 = *(const u16x8*)vr;
        u16x8 vv1 = *(const u16x8*)(vr + 8);
        float4 f0 = {b2f(vv0[0]), b2f(vv0[1]), b2f(vv0[2]), b2f(vv0[3])};
        float4 f1 = {b2f(vv0[4]), b2f(vv0[5]), b2f(vv0[6]), b2f(vv0[7])};
        float4 f2 = {b2f(vv1[0]), b2f(vv1[1]), b2f(vv1[2]), b2f(vv1[3])};
        float4 f3 = {b2f(vv1[4]), b2f(vv1[5]), b2f(vv1[6]), b2f(vv1[7])};
        *(float4*)&Vs[s * 72 + i0] = f0;
        *(float4*)&Vs[s * 72 + i0 + 4] = f1;
        *(float4*)&Vs[s * 72 + i0 + 8] = f2;
        *(float4*)&Vs[s * 72 + i0 + 12] = f3;
    }
    __syncthreads();
    if (tid < 64) {
        w1s[tid] = exp2f(Ls1[63] - Ls1[tid]);
        w2s[tid] = exp2f(Ls2[63] - Ls2[tid]);
    }
    __syncthreads();
    int ii = tid >> 2, jg = tid & 3;
    int vb = jg << 4;
    float acc1[16] = {}, acc2[16] = {};
    float az1 = 0.f, az2 = 0.f;
    for (int s = 0; s < 64; s++) {
        float kf = b2f(Kt[ii * 72 + s]);
        float a1 = w1s[s] * kf, a2 = w2s[s] * kf;
        az1 += a1; az2 += a2;
        #pragma unroll
        for (int q = 0; q < 4; q++) {
            float4 v4 = *(const float4*)&Vs[s * 72 + vb + (q << 2)];
            acc1[q * 4 + 0] += a1 * v4.x; acc1[q * 4 + 1] += a1 * v4.y;
            acc1[q * 4 + 2] += a1 * v4.z; acc1[q * 4 + 3] += a1 * v4.w;
            acc2[q * 4 + 0] += a2 * v4.x; acc2[q * 4 + 1] += a2 * v4.y;
            acc2[q * 4 + 2] += a2 * v4.z; acc2[q * 4 + 3] += a2 * v4.w;
        }
    }
    size_t so = (size_t)blockIdx.x * 4096 + ii * 64 + vb;
    #pragma unroll
    for (int q = 0; q < 4; q++) {
        float4 o1 = {acc1[q * 4 + 0], acc1[q * 4 + 1], acc1[q * 4 + 2], acc1[q * 4 + 3]};
        float4 o2 = {acc2[q * 4 + 0], acc2[q * 4 + 1], acc2[q * 4 + 2], acc2[q * 4 + 3]};
        *(float4*)&S1[so + (q << 2)] = o1;
        *(float4*)&S2[so + (q << 2)] = o2;
    }
    if (jg == 0) { z1[(size_t)blockIdx.x * 64 + ii] = az1; z2[(size_t)blockIdx.x * 64 + ii] = az2; }
    if (tid == 0) { P1[blockIdx.x] = exp2f(Ls1[63]); P2[blockIdx.x] = exp2f(Ls2[63]); }
}

// ---------------- pass2: sequential cross-chunk combine (in-place -> entering states) --
__global__ __launch_bounds__(256) void k_pass2(float* __restrict__ S1, float* __restrict__ S2,
                                               float* __restrict__ z1, float* __restrict__ z2,
                                               const float* __restrict__ P1, const float* __restrict__ P2) {
    int bh = blockIdx.x >> 4, part = blockIdx.x & 15;
    int e = part * 256 + threadIdx.x;
    float c1 = 0.f, c2 = 0.f;
    for (int c = 0; c < NCH; c++) {
        int bc = bh * NCH + c;
        size_t idx = (size_t)bc * 4096 + e;
        float p1 = P1[bc], p2 = P2[bc];
        float t1 = S1[idx]; S1[idx] = c1; c1 = c1 * p1 + t1;
        float t2 = S2[idx]; S2[idx] = c2; c2 = c2 * p2 + t2;
    }
    if (part == 0 && threadIdx.x < 64) {
        float y1 = 0.f, y2 = 0.f;
        for (int c = 0; c < NCH; c++) {
            int bc = bh * NCH + c;
            size_t zi = (size_t)bc * 64 + threadIdx.x;
            float p1 = P1[bc], p2 = P2[bc];
            float t1 = z1[zi]; z1[zi] = y1; y1 = y1 * p1 + t1;
            float t2 = z2[zi]; z2[zi] = y2; y2 = y2 * p2 + t2;
        }
    }
}

// ---------------- pass3: per-chunk outputs ---------------------------------------------
__global__ __launch_bounds__(256) void k_pass3(const u16* __restrict__ qh, const u16* __restrict__ kh,
                                               const u16* __restrict__ vh, const float* __restrict__ lb1,
                                               const float* __restrict__ lb2, const float* __restrict__ S1,
                                               const float* __restrict__ S2, const float* __restrict__ z1,
                                               const float* __restrict__ z2, const float* __restrict__ mask,
                                               u16* __restrict__ obf) {
    __shared__ u16 Qs[64 * 72];     // Qs[t][d]
    __shared__ u16 KtAW[64 * 72];   // first Kt[d][s], later AW[t][s]
    __shared__ u16 Vs2[64 * 72];    // V[s][j] bf16
    __shared__ float H1s[64 * 68];  // H1[i][j]
    __shared__ float H2s[64 * 68];
    __shared__ float Ls1[64], Ls2[64], Z1s[64], Z2s[64];
    int tid = threadIdx.x;
    int bh = blockIdx.x >> 5, c = blockIdx.x & 31;
    int wave = tid >> 6, lane = tid & 63;
    size_t base = ((size_t)bh * S_ + c * CL) * DH;
    if (wave == 0) {
        float v = lb1[(size_t)bh * S_ + c * CL + lane];
        #pragma unroll
        for (int d = 1; d < 64; d <<= 1) { float o = __shfl_up(v, d, 64); if (lane >= d) v += o; }
        Ls1[lane] = v;
    } else if (wave == 1) {
        float v = lb2[(size_t)bh * S_ + c * CL + lane];
        #pragma unroll
        for (int d = 1; d < 64; d <<= 1) { float o = __shfl_up(v, d, 64); if (lane >= d) v += o; }
        Ls2[lane] = v;
    } else if (wave == 2) {
        Z1s[lane] = z1[(size_t)blockIdx.x * 64 + lane];
    } else {
        Z2s[lane] = z2[(size_t)blockIdx.x * 64 + lane];
    }
    {   // stage Q, Kt(transposed), V, H1, H2
        int s = tid >> 2, i0 = (tid & 3) << 4;
        const u16* qr = qh + base + (size_t)s * DH + i0;
        u16x8 q0 = *(const u16x8*)qr;
        u16x8 q1 = *(const u16x8*)(qr + 8);
        *(u16x4*)&Qs[s * 72 + i0]      = u16x4{q0[0], q0[1], q0[2], q0[3]};
        *(u16x4*)&Qs[s * 72 + i0 + 4]  = u16x4{q0[4], q0[5], q0[6], q0[7]};
        *(u16x4*)&Qs[s * 72 + i0 + 8]  = u16x4{q1[0], q1[1], q1[2], q1[3]};
        *(u16x4*)&Qs[s * 72 + i0 + 12] = u16x4{q1[4], q1[5], q1[6], q1[7]};
        const u16* kr = kh + base + (size_t)s * DH + i0;
        u16x8 kk0 = *(const u16x8*)kr;
        u16x8 kk1 = *(const u16x8*)(kr + 8);
        #pragma unroll
        for (int q = 0; q < 8; q++) { KtAW[(i0 + q) * 72 + s] = kk0[q]; KtAW[(i0 + 8 + q) * 72 + s] = kk1[q]; }
        const u16* vr = vh + base + (size_t)s * DH + i0;
        u16x8 vv0 = *(const u16x8*)vr;
        u16x8 vv1 = *(const u16x8*)(vr + 8);
        *(u16x4*)&Vs2[s * 72 + i0]      = u16x4{vv0[0], vv0[1], vv0[2], vv0[3]};
        *(u16x4*)&Vs2[s * 72 + i0 + 4]  = u16x4{vv0[4], vv0[5], vv0[6], vv0[7]};
        *(u16x4*)&Vs2[s * 72 + i0 + 8]  = u16x4{vv1[0], vv1[1], vv1[2], vv1[3]};
        *(u16x4*)&Vs2[s * 72 + i0 + 12] = u16x4{vv1[4], vv1[5], vv1[6], vv1[7]};
        size_t hbase = (size_t)blockIdx.x * 4096 + s * 64 + i0;
        #pragma unroll
        for (int q = 0; q < 4; q++) {
            float4 h1 = *(const float4*)&S1[hbase + (q << 2)];
            float4 h2 = *(const float4*)&S2[hbase + (q << 2)];
            *(float4*)&H1s[s * 68 + i0 + (q << 2)] = h1;
            *(float4*)&H2s[s * 68 + i0 + (q << 2)] = h2;
        }
    }
    __syncthreads();
    int tt = tid >> 2, jg = tid & 3;
    int vb = jg << 4;
    // --- A-step: A[tt][s] = sum_d Q[tt][d]*K[s][d]
    float accA[16] = {};
    for (int d = 0; d < 64; d++) {
        float qf = b2f(Qs[tt * 72 + d]);
        #pragma unroll
        for (int q = 0; q < 4; q++) {
            u16x4 k4 = *(const u16x4*)&KtAW[d * 72 + vb + (q << 2)];
            accA[q * 4 + 0] += qf * b2f(k4[0]); accA[q * 4 + 1] += qf * b2f(k4[1]);
            accA[q * 4 + 2] += qf * b2f(k4[2]); accA[q * 4 + 3] += qf * b2f(k4[3]);
        }
    }
    float l1t = Ls1[tt], l2t = Ls2[tt];
    __syncthreads();  // everyone done reading Kt before AW overwrite
    #pragma unroll
    for (int q = 0; q < 4; q++) {
        u16x4 aw;
        #pragma unroll
        for (int j = 0; j < 4; j++) {
            int sCol = vb + (q << 2) + j;
            float w = 0.f;
            if (sCol <= tt) w = exp2f(l1t - Ls1[sCol]) + exp2f(l2t - Ls2[sCol]);
            aw[j] = f2b(accA[q * 4 + j] * w);
        }
        *(u16x4*)&KtAW[tt * 72 + vb + (q << 2)] = aw;
    }
    __syncthreads();
    // --- AW@V + attention-denominator
    float accn[16] = {}, accden = 0.f;
    for (int s2 = 0; s2 < 64; s2++) {
        float aw = b2f(KtAW[tt * 72 + s2]);
        accden += aw;
        #pragma unroll
        for (int q = 0; q < 4; q++) {
            u16x4 v4 = *(const u16x4*)&Vs2[s2 * 72 + vb + (q << 2)];
            accn[q * 4 + 0] += aw * b2f(v4[0]); accn[q * 4 + 1] += aw * b2f(v4[1]);
            accn[q * 4 + 2] += aw * b2f(v4[2]); accn[q * 4 + 3] += aw * b2f(v4[3]);
        }
    }
    // --- cross terms: Q@H1, Q@H2, q.Z1, q.Z2
    float acc1[16] = {}, acc2[16] = {};
    float az1 = 0.f, az2 = 0.f;
    for (int i2 = 0; i2 < 64; i2++) {
        float qf = b2f(Qs[tt * 72 + i2]);
        az1 += qf * Z1s[i2];
        az2 += qf * Z2s[i2];
        #pragma unroll
        for (int q = 0; q < 4; q++) {
            float4 h14 = *(const float4*)&H1s[i2 * 68 + vb + (q << 2)];
            float4 h24 = *(const float4*)&H2s[i2 * 68 + vb + (q << 2)];
            acc1[q * 4 + 0] += qf * h14.x; acc1[q * 4 + 1] += qf * h14.y;
            acc1[q * 4 + 2] += qf * h14.z; acc1[q * 4 + 3] += qf * h14.w;
            acc2[q * 4 + 0] += qf * h24.x; acc2[q * 4 + 1] += qf * h24.y;
            acc2[q * 4 + 2] += qf * h24.z; acc2[q * 4 + 3] += qf * h24.w;
        }
    }
    float e1 = exp2f(l1t), e2 = exp2f(l2t);
    float den = accden + e1 * az1 + e2 * az2;
    den = fmaxf(den, 1e-6f);
    int b = bh >> 3, hh = bh & 7, sg = c * CL + tt;
    float mv = mask[(size_t)b * S_ + sg];
    float inv = mv / den;
    u16* op = obf + ((size_t)b * S_ + sg) * DM + hh * DH + vb;
    #pragma unroll
    for (int q = 0; q < 16; q++) {
        float numv = accn[q] + e1 * acc1[q] + e2 * acc2[q];
        op[q] = f2b(numv * inv);
    }
}

extern "C" void kernel_launch(void* const* d_in, const int* in_sizes, int n_in,
                              void* d_out, int out_size, void* d_ws, size_t ws_size,
                              hipStream_t stream) {
    const float* x    = (const float*)d_in[0];
    const float* mask = (const float*)d_in[1];
    const float* Wq   = (const float*)d_in[2];
    const float* Wk   = (const float*)d_in[3];
    const float* Wv   = (const float*)d_in[4];
    const float* Wb   = (const float*)d_in[5];
    const float* bb   = (const float*)d_in[6];
    const float* Wo   = (const float*)d_in[7];
    const float* bo   = (const float*)d_in[8];
    const float* lnw  = (const float*)d_in[9];
    const float* rec  = (const float*)d_in[10];
    const float* bb1  = (const float*)d_in[11];
    const float* bb2  = (const float*)d_in[12];
    float* out = (float*)d_out;

    char* w = (char*)d_ws;
    u16* h    = (u16*)w;  w += (size_t)8192 * 512 * 2;
    u16* wcat = (u16*)w;  w += (size_t)1536 * 512 * 2;
    u16* wo   = (u16*)w;  w += (size_t)512 * 512 * 2;
    u16* qh   = (u16*)w;  w += (size_t)8192 * 512 * 2;
    u16* kh   = (u16*)w;  w += (size_t)8192 * 512 * 2;
    u16* vh   = (u16*)w;  w += (size_t)8192 * 512 * 2;
    float* lb1 = (float*)w; w += (size_t)32 * 2048 * 4;
    float* lb2 = (float*)w; w += (size_t)32 * 2048 * 4;
    float* S1  = (float*)w; w += (size_t)1024 * 4096 * 4;
    float* S2  = (float*)w; w += (size_t)1024 * 4096 * 4;
    float* z1  = (float*)w; w += (size_t)1024 * 64 * 4;
    float* z2  = (float*)w; w += (size_t)1024 * 64 * 4;
    float* P1  = (float*)w; w += 4096;
    float* P2  = (float*)w; w += 4096;
    u16* obf   = (u16*)w;   w += (size_t)8192 * 512 * 2;

    k_rmsnorm<<<2048, 256, 0, stream>>>(x, lnw, h);
    k_convw<<<1024, 256, 0, stream>>>(Wq, Wk, Wv, Wo, wcat, wo);
    k_gemm<0><<<dim3(64, 12), 256, 0, stream>>>(h, wcat, 512, mask, qh, kh, vh, nullptr, nullptr, nullptr);
    k_beta<<<2048, 256, 0, stream>>>(h, Wb, bb, rec, bb1, bb2, lb1, lb2);
    k_pass1<<<1024, 256, 0, stream>>>(kh, vh, lb1, lb2, S1, S2, z1, z2, P1, P2);
    k_pass2<<<512, 256, 0, stream>>>(S1, S2, z1, z2, P1, P2);
    k_pass3<<<1024, 256, 0, stream>>>(qh, kh, vh, lb1, lb2, S1, S2, z1, z2, mask, obf);
    k_gemm<1><<<dim3(64, 4), 256, 0, stream>>>(obf, wo, 512, nullptr, nullptr, nullptr, nullptr, x, bo, out);
}

// Round 2
// 121.092 us; speedup vs baseline: 1.3807x; 1.3807x over previous
//
#include <hip/hip_runtime.h>
#include <stdint.h>

typedef unsigned short u16;
typedef short bf16x8 __attribute__((ext_vector_type(8)));
typedef unsigned short u16x8 __attribute__((ext_vector_type(8)));
typedef unsigned short u16x4 __attribute__((ext_vector_type(4)));
typedef float f32x4 __attribute__((ext_vector_type(4)));

#define S_ 2048
#define DM 512
#define DH 64
#define CL 64           // chunk length
#define NCH 32          // chunks per sequence = 2048/64

// swizzled LDS index (u16 elements): row stride 72 elems (144B, 16B-mult),
// XOR bits 3..5 of elem index with row&7 -> b128 reads stay 16B aligned,
// transpose scalar writes spread across all banks.
#define SW(r, sc) ((r) * 72 + ((sc) ^ (((r) & 7) << 3)))

__device__ __forceinline__ float b2f(u16 u) { return __uint_as_float(((unsigned)u) << 16); }
__device__ __forceinline__ u16 f2b(float f) {
    unsigned v = __float_as_uint(f);
    unsigned r = v + 0x7fffu + ((v >> 16) & 1u);
    return (u16)(r >> 16);
}
__device__ __forceinline__ float phi_elu(float x) { return x > 0.f ? x + 1.f : __expf(x); }
__device__ __forceinline__ float clip01(float v) { return fminf(fmaxf(v, 0.01f), 0.995f); }

// ---------------- RMSNorm ----------------
__global__ __launch_bounds__(256) void k_rmsnorm(const float* __restrict__ x,
                                                 const float* __restrict__ lnw,
                                                 u16* __restrict__ h) {
    int wave = threadIdx.x >> 6, lane = threadIdx.x & 63;
    int row = blockIdx.x * 4 + wave;
    const float* xr = x + (size_t)row * DM + lane * 8;
    float4 v0 = *(const float4*)xr;
    float4 v1 = *(const float4*)(xr + 4);
    float ss = v0.x * v0.x + v0.y * v0.y + v0.z * v0.z + v0.w * v0.w +
               v1.x * v1.x + v1.y * v1.y + v1.z * v1.z + v1.w * v1.w;
    #pragma unroll
    for (int off = 32; off; off >>= 1) ss += __shfl_xor(ss, off, 64);
    float sc = rsqrtf(ss * (1.f / DM) + 1e-5f);
    const float* wr_ = lnw + lane * 8;
    float4 w0 = *(const float4*)wr_;
    float4 w1 = *(const float4*)(wr_ + 4);
    u16x8 o;
    o[0] = f2b(v0.x * sc * w0.x); o[1] = f2b(v0.y * sc * w0.y);
    o[2] = f2b(v0.z * sc * w0.z); o[3] = f2b(v0.w * sc * w0.w);
    o[4] = f2b(v1.x * sc * w1.x); o[5] = f2b(v1.y * sc * w1.y);
    o[6] = f2b(v1.z * sc * w1.z); o[7] = f2b(v1.w * sc * w1.w);
    *(u16x8*)(h + (size_t)row * DM + lane * 8) = o;
}

// ---------------- weights -> bf16 ----------------
__global__ __launch_bounds__(256) void k_convw(const float* __restrict__ Wq, const float* __restrict__ Wk,
                                               const float* __restrict__ Wv, const float* __restrict__ Wo,
                                               u16* __restrict__ wcat, u16* __restrict__ wo) {
    int idx = blockIdx.x * 256 + threadIdx.x;
    int e0 = idx << 2;
    if (e0 < 1536 * 512) {
        int r = e0 >> 9, ccol = e0 & 511;
        const float* src = (r < 512) ? (Wq + (size_t)r * 512)
                         : (r < 1024) ? (Wk + (size_t)(r - 512) * 512)
                                      : (Wv + (size_t)(r - 1024) * 512);
        float4 v = *(const float4*)(src + ccol);
        u16x4 o = {f2b(v.x), f2b(v.y), f2b(v.z), f2b(v.w)};
        *(u16x4*)(wcat + e0) = o;
    } else {
        int e = e0 - 1536 * 512;
        float4 v = *(const float4*)(Wo + e);
        u16x4 o = {f2b(v.x), f2b(v.y), f2b(v.z), f2b(v.w)};
        *(u16x4*)(wo + e) = o;
    }
}

// ---------------- MFMA bf16 GEMM 128x128 tile ----------------
template<int MODE>
__global__ __launch_bounds__(256) void k_gemm(const u16* __restrict__ A, const u16* __restrict__ Bw, int K,
                                              const float* __restrict__ mask, u16* __restrict__ qh,
                                              u16* __restrict__ kh, u16* __restrict__ vh,
                                              const float* __restrict__ xres, const float* __restrict__ bo,
                                              float* __restrict__ outp) {
    __shared__ u16 As[128 * 40];
    __shared__ u16 Bs[128 * 40];
    int tid = threadIdx.x;
    int lane = tid & 63, wave = tid >> 6;
    int wr = wave >> 1, wc = wave & 1;
    int m0 = blockIdx.x * 128, n0 = blockIdx.y * 128;
    f32x4 acc[4][4] = {};
    int srow = tid >> 2, sc8 = (tid & 3) << 3;
    const u16* Ag0 = A + (size_t)(m0 + srow) * K + sc8;
    const u16* Ag1 = Ag0 + (size_t)64 * K;
    const u16* Bg0 = Bw + (size_t)(n0 + srow) * K + sc8;
    const u16* Bg1 = Bg0 + (size_t)64 * K;
    u16* As0 = &As[srow * 40 + sc8];
    u16* As1 = &As[(srow + 64) * 40 + sc8];
    u16* Bs0 = &Bs[srow * 40 + sc8];
    u16* Bs1 = &Bs[(srow + 64) * 40 + sc8];
    int kh8 = (lane >> 4) << 3;
    for (int k0 = 0; k0 < K; k0 += 32) {
        u16x8 a0 = *(const u16x8*)(Ag0 + k0);
        u16x8 a1 = *(const u16x8*)(Ag1 + k0);
        u16x8 b0 = *(const u16x8*)(Bg0 + k0);
        u16x8 b1 = *(const u16x8*)(Bg1 + k0);
        if (k0) __syncthreads();
        *(u16x8*)As0 = a0; *(u16x8*)As1 = a1;
        *(u16x8*)Bs0 = b0; *(u16x8*)Bs1 = b1;
        __syncthreads();
        bf16x8 af[4], bfr[4];
        #pragma unroll
        for (int m = 0; m < 4; m++) af[m] = *(const bf16x8*)&As[(wr * 64 + m * 16 + (lane & 15)) * 40 + kh8];
        #pragma unroll
        for (int n = 0; n < 4; n++) bfr[n] = *(const bf16x8*)&Bs[(wc * 64 + n * 16 + (lane & 15)) * 40 + kh8];
        #pragma unroll
        for (int m = 0; m < 4; m++)
            #pragma unroll
            for (int n = 0; n < 4; n++)
                acc[m][n] = __builtin_amdgcn_mfma_f32_16x16x32_bf16(af[m], bfr[n], acc[m][n], 0, 0, 0);
    }
    #pragma unroll
    for (int m = 0; m < 4; m++) {
        int rbase = m0 + wr * 64 + m * 16 + ((lane >> 4) << 2);
        #pragma unroll
        for (int n = 0; n < 4; n++) {
            int col = n0 + wc * 64 + n * 16 + (lane & 15);
            #pragma unroll
            for (int r = 0; r < 4; r++) {
                int row = rbase + r;
                float v = acc[m][n][r];
                if constexpr (MODE == 0) {
                    int mat = col >> 9, f = col & 511, hh = f >> 6, j = f & 63;
                    int b = row >> 11, s = row & 2047;
                    size_t di = ((size_t)((b << 3) + hh) * S_ + s) * DH + j;
                    if (mat == 0) qh[di] = f2b(phi_elu(v));
                    else if (mat == 1) kh[di] = f2b(phi_elu(v) * mask[(b << 11) + s]);
                    else vh[di] = f2b(v);
                } else {
                    size_t oi = (size_t)row * DM + col;
                    outp[oi] = v + xres[oi] + bo[col];
                }
            }
        }
    }
}

// ---------------- beta + log2 decays ----------------
__global__ __launch_bounds__(256) void k_beta(const u16* __restrict__ h, const float* __restrict__ Wb,
                                              const float* __restrict__ bb, const float* __restrict__ rec,
                                              const float* __restrict__ bb1p, const float* __restrict__ bb2p,
                                              float* __restrict__ lb1, float* __restrict__ lb2) {
    int wave = threadIdx.x >> 6, lane = threadIdx.x & 63;
    int row = blockIdx.x * 4 + wave;
    const u16* hr = h + (size_t)row * DM + lane * 8;
    u16x8 hu = *(const u16x8*)hr;
    float hv[8];
    #pragma unroll
    for (int j = 0; j < 8; j++) hv[j] = b2f(hu[j]);
    float acc[8];
    #pragma unroll
    for (int hd = 0; hd < 8; hd++) {
        const float* wp = Wb + hd * DM + lane * 8;
        float4 w0 = *(const float4*)wp;
        float4 w1 = *(const float4*)(wp + 4);
        acc[hd] = hv[0] * w0.x + hv[1] * w0.y + hv[2] * w0.z + hv[3] * w0.w +
                  hv[4] * w1.x + hv[5] * w1.y + hv[6] * w1.z + hv[7] * w1.w;
    }
    #pragma unroll
    for (int hd = 0; hd < 8; hd++) {
        #pragma unroll
        for (int off = 32; off; off >>= 1) acc[hd] += __shfl_xor(acc[hd], off, 64);
    }
    if (lane == 0) {
        float b1b = clip01(1.f / (1.f + __expf(-bb1p[0])));
        float b2b = clip01(1.f / (1.f + __expf(-bb2p[0])));
        int b = row >> 11, s = row & 2047;
        #pragma unroll
        for (int hd = 0; hd < 8; hd++) {
            float logit = acc[hd] + bb[hd] + rec[hd];
            float beta = 1.f / (1.f + __expf(-logit));
            float bin = clip01(beta);
            float b1 = clip01(b1b * bin);
            float b2 = clip01(b2b * bin);
            size_t o = (size_t)((b << 3) + hd) * S_ + s;
            lb1[o] = log2f(b1);
            lb2[o] = log2f(b2);
        }
    }
}

// ---------------- pass1 (MFMA): per-chunk S1^T,S2^T (64x64 f32), z1,z2, P1,P2 ---------
__global__ __launch_bounds__(256) void k_pass1(const u16* __restrict__ kh, const u16* __restrict__ vh,
                                               const float* __restrict__ lb1, const float* __restrict__ lb2,
                                               float* __restrict__ S1, float* __restrict__ S2,
                                               float* __restrict__ z1, float* __restrict__ z2,
                                               float* __restrict__ P1, float* __restrict__ P2) {
    __shared__ u16 Kw1[64 * 72];   // [i][s] = bf16(w1[s]*k[s][i]), swizzled
    __shared__ u16 Kw2[64 * 72];
    __shared__ u16 Vt[64 * 72];    // [j][s] = v[s][j]
    __shared__ float Ls1[64], Ls2[64];
    int tid = threadIdx.x;
    int bh = blockIdx.x >> 5, c = blockIdx.x & 31;
    int wave = tid >> 6, lane = tid & 63;
    size_t base = ((size_t)bh * S_ + c * CL) * DH;
    if (wave == 0) {
        float v = lb1[(size_t)bh * S_ + c * CL + lane];
        #pragma unroll
        for (int d = 1; d < 64; d <<= 1) { float o = __shfl_up(v, d, 64); if (lane >= d) v += o; }
        Ls1[lane] = v;
    } else if (wave == 1) {
        float v = lb2[(size_t)bh * S_ + c * CL + lane];
        #pragma unroll
        for (int d = 1; d < 64; d <<= 1) { float o = __shfl_up(v, d, 64); if (lane >= d) v += o; }
        Ls2[lane] = v;
    }
    // staging thread mapping: s-major so transpose writes hit all 32 banks
    int ss = tid & 63, i0 = (tid >> 6) << 4;
    const u16* kr = kh + base + (size_t)ss * DH + i0;
    u16x8 kk0 = *(const u16x8*)kr;
    u16x8 kk1 = *(const u16x8*)(kr + 8);
    {
        const u16* vr = vh + base + (size_t)ss * DH + i0;
        u16x8 vv0 = *(const u16x8*)vr;
        u16x8 vv1 = *(const u16x8*)(vr + 8);
        #pragma unroll
        for (int j = 0; j < 8; j++) {
            Vt[SW(i0 + j, ss)] = vv0[j];
            Vt[SW(i0 + 8 + j, ss)] = vv1[j];
        }
    }
    __syncthreads();
    float w1 = exp2f(Ls1[63] - Ls1[ss]);
    float w2 = exp2f(Ls2[63] - Ls2[ss]);
    #pragma unroll
    for (int j = 0; j < 8; j++) {
        float k0 = b2f(kk0[j]), k1 = b2f(kk1[j]);
        Kw1[SW(i0 + j, ss)] = f2b(w1 * k0);
        Kw2[SW(i0 + j, ss)] = f2b(w2 * k0);
        Kw1[SW(i0 + 8 + j, ss)] = f2b(w1 * k1);
        Kw2[SW(i0 + 8 + j, ss)] = f2b(w2 * k1);
    }
    if (tid == 0) { P1[blockIdx.x] = exp2f(Ls1[63]); P2[blockIdx.x] = exp2f(Ls2[63]); }
    __syncthreads();
    // MFMA: C[j][i] = sum_s Vt[j][s] * Kw[i][s]
    int l15 = lane & 15, kh8 = (lane >> 4) << 3;
    int j0 = wave << 4;
    bf16x8 vf0 = *(const bf16x8*)&Vt[SW(j0 + l15, kh8)];
    bf16x8 vf1 = *(const bf16x8*)&Vt[SW(j0 + l15, 32 + kh8)];
    f32x4 a1[4], a2[4];
    #pragma unroll
    for (int it = 0; it < 4; it++) { a1[it] = (f32x4){0,0,0,0}; a2[it] = (f32x4){0,0,0,0}; }
    #pragma unroll
    for (int it = 0; it < 4; it++) {
        int ir = (it << 4) + l15;
        bf16x8 b0 = *(const bf16x8*)&Kw1[SW(ir, kh8)];
        bf16x8 b1 = *(const bf16x8*)&Kw1[SW(ir, 32 + kh8)];
        a1[it] = __builtin_amdgcn_mfma_f32_16x16x32_bf16(vf0, b0, a1[it], 0, 0, 0);
        a1[it] = __builtin_amdgcn_mfma_f32_16x16x32_bf16(vf1, b1, a1[it], 0, 0, 0);
        bf16x8 c0 = *(const bf16x8*)&Kw2[SW(ir, kh8)];
        bf16x8 c1 = *(const bf16x8*)&Kw2[SW(ir, 32 + kh8)];
        a2[it] = __builtin_amdgcn_mfma_f32_16x16x32_bf16(vf0, c0, a2[it], 0, 0, 0);
        a2[it] = __builtin_amdgcn_mfma_f32_16x16x32_bf16(vf1, c1, a2[it], 0, 0, 0);
    }
    // z1[i] = sum_s Kw1[i][s]  (row sums, VALU)
    {
        int iz = tid >> 2, sg = tid & 3;
        u16x8 x0 = *(const u16x8*)&Kw1[SW(iz, sg << 4)];
        u16x8 x1 = *(const u16x8*)&Kw1[SW(iz, (sg << 4) + 8)];
        u16x8 y0 = *(const u16x8*)&Kw2[SW(iz, sg << 4)];
        u16x8 y1 = *(const u16x8*)&Kw2[SW(iz, (sg << 4) + 8)];
        float z1v = 0.f, z2v = 0.f;
        #pragma unroll
        for (int j = 0; j < 8; j++) {
            z1v += b2f(x0[j]) + b2f(x1[j]);
            z2v += b2f(y0[j]) + b2f(y1[j]);
        }
        z1v += __shfl_xor(z1v, 1, 64); z1v += __shfl_xor(z1v, 2, 64);
        z2v += __shfl_xor(z2v, 1, 64); z2v += __shfl_xor(z2v, 2, 64);
        if (sg == 0) {
            z1[(size_t)blockIdx.x * 64 + iz] = z1v;
            z2[(size_t)blockIdx.x * 64 + iz] = z2v;
        }
    }
    // store S^T f32
    int jr0 = j0 + ((lane >> 4) << 2);
    #pragma unroll
    for (int it = 0; it < 4; it++) {
        int ii = (it << 4) + l15;
        #pragma unroll
        for (int r = 0; r < 4; r++) {
            size_t o = (size_t)blockIdx.x * 4096 + (size_t)(jr0 + r) * 64 + ii;
            S1[o] = a1[it][r];
            S2[o] = a2[it][r];
        }
    }
}

// ---------------- pass2: cross-chunk scan (unchanged; operates elementwise) -----------
__global__ __launch_bounds__(256) void k_pass2(float* __restrict__ S1, float* __restrict__ S2,
                                               float* __restrict__ z1, float* __restrict__ z2,
                                               const float* __restrict__ P1, const float* __restrict__ P2) {
    int bh = blockIdx.x >> 4, part = blockIdx.x & 15;
    int e = part * 256 + threadIdx.x;
    float c1 = 0.f, c2 = 0.f;
    for (int c = 0; c < NCH; c++) {
        int bc = bh * NCH + c;
        size_t idx = (size_t)bc * 4096 + e;
        float p1 = P1[bc], p2 = P2[bc];
        float t1 = S1[idx]; S1[idx] = c1; c1 = c1 * p1 + t1;
        float t2 = S2[idx]; S2[idx] = c2; c2 = c2 * p2 + t2;
    }
    if (part == 0 && threadIdx.x < 64) {
        float y1 = 0.f, y2 = 0.f;
        for (int c = 0; c < NCH; c++) {
            int bc = bh * NCH + c;
            size_t zi = (size_t)bc * 64 + threadIdx.x;
            float p1 = P1[bc], p2 = P2[bc];
            float t1 = z1[zi]; z1[zi] = y1; y1 = y1 * p1 + t1;
            float t2 = z2[zi]; z2[zi] = y2; y2 = y2 * p2 + t2;
        }
    }
}

// ---------------- pass3 (MFMA): per-chunk outputs -------------------------------------
__global__ __launch_bounds__(256) void k_pass3(const u16* __restrict__ qh, const u16* __restrict__ kh,
                                               const u16* __restrict__ vh, const float* __restrict__ lb1,
                                               const float* __restrict__ lb2, const float* __restrict__ S1,
                                               const float* __restrict__ S2, const float* __restrict__ z1,
                                               const float* __restrict__ z2, const float* __restrict__ mask,
                                               u16* __restrict__ obf) {
    __shared__ u16 Vt[64 * 72];    // [j][s]
    __shared__ u16 H1s[64 * 72];   // [j][i] = H1[i][j] bf16
    __shared__ u16 H2s[64 * 72];
    __shared__ u16 AWs[64 * 72];   // [t][s]
    __shared__ float Ls1[64], Ls2[64], dens[64], qZ1[64], qZ2[64];
    int tid = threadIdx.x;
    int bh = blockIdx.x >> 5, c = blockIdx.x & 31;
    int wave = tid >> 6, lane = tid & 63;
    size_t base = ((size_t)bh * S_ + c * CL) * DH;
    if (wave == 0) {
        float v = lb1[(size_t)bh * S_ + c * CL + lane];
        #pragma unroll
        for (int d = 1; d < 64; d <<= 1) { float o = __shfl_up(v, d, 64); if (lane >= d) v += o; }
        Ls1[lane] = v;
    } else if (wave == 1) {
        float v = lb2[(size_t)bh * S_ + c * CL + lane];
        #pragma unroll
        for (int d = 1; d < 64; d <<= 1) { float o = __shfl_up(v, d, 64); if (lane >= d) v += o; }
        Ls2[lane] = v;
    }
    // --- stage V^T (s-major transpose, conflict-free-ish)
    {
        int ss = tid & 63, i0 = (tid >> 6) << 4;
        const u16* vr = vh + base + (size_t)ss * DH + i0;
        u16x8 vv0 = *(const u16x8*)vr;
        u16x8 vv1 = *(const u16x8*)(vr + 8);
        #pragma unroll
        for (int j = 0; j < 8; j++) {
            Vt[SW(i0 + j, ss)] = vv0[j];
            Vt[SW(i0 + 8 + j, ss)] = vv1[j];
        }
    }
    // --- stage H1,H2 (copy-convert f32 -> bf16)
    {
        int j = tid >> 2, i04 = (tid & 3) << 4;
        const float* s1p = S1 + (size_t)blockIdx.x * 4096 + (size_t)j * 64 + i04;
        const float* s2p = S2 + (size_t)blockIdx.x * 4096 + (size_t)j * 64 + i04;
        float4 a0 = *(const float4*)s1p;
        float4 a1 = *(const float4*)(s1p + 4);
        float4 a2 = *(const float4*)(s1p + 8);
        float4 a3 = *(const float4*)(s1p + 12);
        u16x8 h0 = {f2b(a0.x), f2b(a0.y), f2b(a0.z), f2b(a0.w), f2b(a1.x), f2b(a1.y), f2b(a1.z), f2b(a1.w)};
        u16x8 h1 = {f2b(a2.x), f2b(a2.y), f2b(a2.z), f2b(a2.w), f2b(a3.x), f2b(a3.y), f2b(a3.z), f2b(a3.w)};
        *(u16x8*)&H1s[SW(j, i04)] = h0;
        *(u16x8*)&H1s[SW(j, i04 + 8)] = h1;
        float4 b0 = *(const float4*)s2p;
        float4 b1 = *(const float4*)(s2p + 4);
        float4 b2 = *(const float4*)(s2p + 8);
        float4 b3 = *(const float4*)(s2p + 12);
        u16x8 g0 = {f2b(b0.x), f2b(b0.y), f2b(b0.z), f2b(b0.w), f2b(b1.x), f2b(b1.y), f2b(b1.z), f2b(b1.w)};
        u16x8 g1 = {f2b(b2.x), f2b(b2.y), f2b(b2.z), f2b(b2.w), f2b(b3.x), f2b(b3.y), f2b(b3.z), f2b(b3.w)};
        *(u16x8*)&H2s[SW(j, i04)] = g0;
        *(u16x8*)&H2s[SW(j, i04 + 8)] = g1;
    }
    // --- qZ dots: qZ1[t] = sum_i q[t][i]*Z1[i]
    {
        int t = tid >> 2, g = tid & 3;
        const u16* qp = qh + base + (size_t)t * DH + (g << 4);
        u16x8 q0 = *(const u16x8*)qp;
        u16x8 q1 = *(const u16x8*)(qp + 8);
        const float* z1p = z1 + (size_t)blockIdx.x * 64 + (g << 4);
        const float* z2p = z2 + (size_t)blockIdx.x * 64 + (g << 4);
        float az1 = 0.f, az2 = 0.f;
        #pragma unroll
        for (int m = 0; m < 8; m++) {
            float qv0 = b2f(q0[m]), qv1 = b2f(q1[m]);
            az1 += qv0 * z1p[m] + qv1 * z1p[m + 8];
            az2 += qv0 * z2p[m] + qv1 * z2p[m + 8];
        }
        az1 += __shfl_xor(az1, 1, 64); az1 += __shfl_xor(az1, 2, 64);
        az2 += __shfl_xor(az2, 1, 64); az2 += __shfl_xor(az2, 2, 64);
        if (g == 0) { qZ1[t] = az1; qZ2[t] = az2; }
    }
    // --- A-phase: A = Q K^T via MFMA with global-direct fragments (L2-resident)
    int l15 = lane & 15, kh8 = (lane >> 4) << 3;
    int t0 = wave << 4;
    const u16* qb = qh + base + (size_t)(t0 + l15) * DH;
    bf16x8 qf0 = *(const bf16x8*)(qb + kh8);
    bf16x8 qf1 = *(const bf16x8*)(qb + 32 + kh8);
    f32x4 accA[4];
    #pragma unroll
    for (int st = 0; st < 4; st++) accA[st] = (f32x4){0, 0, 0, 0};
    #pragma unroll
    for (int st = 0; st < 4; st++) {
        const u16* kb = kh + base + (size_t)((st << 4) + l15) * DH;
        bf16x8 kf0 = *(const bf16x8*)(kb + kh8);
        bf16x8 kf1 = *(const bf16x8*)(kb + 32 + kh8);
        accA[st] = __builtin_amdgcn_mfma_f32_16x16x32_bf16(qf0, kf0, accA[st], 0, 0, 0);
        accA[st] = __builtin_amdgcn_mfma_f32_16x16x32_bf16(qf1, kf1, accA[st], 0, 0, 0);
    }
    __syncthreads();
    // --- W phase: decay-mask, bf16 round, write AWs, row-sum -> dens
    int trow = t0 + ((lane >> 4) << 2);
    float l1t[4], l2t[4];
    #pragma unroll
    for (int r = 0; r < 4; r++) { l1t[r] = Ls1[trow + r]; l2t[r] = Ls2[trow + r]; }
    float rs[4] = {0.f, 0.f, 0.f, 0.f};
    #pragma unroll
    for (int st = 0; st < 4; st++) {
        int s = (st << 4) + l15;
        float s1 = Ls1[s], s2 = Ls2[s];
        #pragma unroll
        for (int r = 0; r < 4; r++) {
            float w = 0.f;
            if (s <= trow + r) w = exp2f(l1t[r] - s1) + exp2f(l2t[r] - s2);
            u16 awb = f2b(accA[st][r] * w);
            AWs[SW(trow + r, s)] = awb;
            rs[r] += b2f(awb);
        }
    }
    #pragma unroll
    for (int off = 1; off < 16; off <<= 1) {
        #pragma unroll
        for (int r = 0; r < 4; r++) rs[r] += __shfl_xor(rs[r], off, 64);
    }
    if (l15 == 0) {
        #pragma unroll
        for (int r = 0; r < 4; r++) dens[trow + r] = rs[r];
    }
    __syncthreads();
    // --- phase 2: O_intra = AW @ V ; cross = Q @ H1, Q @ H2
    bf16x8 awf0 = *(const bf16x8*)&AWs[SW(t0 + l15, kh8)];
    bf16x8 awf1 = *(const bf16x8*)&AWs[SW(t0 + l15, 32 + kh8)];
    f32x4 accO[4], accC1[4], accC2[4];
    #pragma unroll
    for (int jt = 0; jt < 4; jt++) {
        accO[jt] = (f32x4){0, 0, 0, 0};
        accC1[jt] = (f32x4){0, 0, 0, 0};
        accC2[jt] = (f32x4){0, 0, 0, 0};
    }
    #pragma unroll
    for (int jt = 0; jt < 4; jt++) {
        int jr = (jt << 4) + l15;
        bf16x8 v0 = *(const bf16x8*)&Vt[SW(jr, kh8)];
        bf16x8 v1 = *(const bf16x8*)&Vt[SW(jr, 32 + kh8)];
        accO[jt] = __builtin_amdgcn_mfma_f32_16x16x32_bf16(awf0, v0, accO[jt], 0, 0, 0);
        accO[jt] = __builtin_amdgcn_mfma_f32_16x16x32_bf16(awf1, v1, accO[jt], 0, 0, 0);
        bf16x8 h10 = *(const bf16x8*)&H1s[SW(jr, kh8)];
        bf16x8 h11 = *(const bf16x8*)&H1s[SW(jr, 32 + kh8)];
        accC1[jt] = __builtin_amdgcn_mfma_f32_16x16x32_bf16(qf0, h10, accC1[jt], 0, 0, 0);
        accC1[jt] = __builtin_amdgcn_mfma_f32_16x16x32_bf16(qf1, h11, accC1[jt], 0, 0, 0);
        bf16x8 h20 = *(const bf16x8*)&H2s[SW(jr, kh8)];
        bf16x8 h21 = *(const bf16x8*)&H2s[SW(jr, 32 + kh8)];
        accC2[jt] = __builtin_amdgcn_mfma_f32_16x16x32_bf16(qf0, h20, accC2[jt], 0, 0, 0);
        accC2[jt] = __builtin_amdgcn_mfma_f32_16x16x32_bf16(qf1, h21, accC2[jt], 0, 0, 0);
    }
    // --- epilogue
    int b = bh >> 3, hh = bh & 7;
    #pragma unroll
    for (int r = 0; r < 4; r++) {
        int t = trow + r;
        float e1 = exp2f(l1t[r]), e2 = exp2f(l2t[r]);
        float den = dens[t] + e1 * qZ1[t] + e2 * qZ2[t];
        den = fmaxf(den, 1e-6f);
        int sg = (c << 6) + t;
        float mv = mask[(size_t)b * S_ + sg];
        float inv = mv / den;
        u16* op = obf + ((size_t)b * S_ + sg) * DM + hh * DH;
        #pragma unroll
        for (int jt = 0; jt < 4; jt++) {
            float numv = accO[jt][r] + e1 * accC1[jt][r] + e2 * accC2[jt][r];
            op[(jt << 4) + l15] = f2b(numv * inv);
        }
    }
}

extern "C" void kernel_launch(void* const* d_in, const int* in_sizes, int n_in,
                              void* d_out, int out_size, void* d_ws, size_t ws_size,
                              hipStream_t stream) {
    const float* x    = (const float*)d_in[0];
    const float* mask = (const float*)d_in[1];
    const float* Wq   = (const float*)d_in[2];
    const float* Wk   = (const float*)d_in[3];
    const float* Wv   = (const float*)d_in[4];
    const float* Wb   = (const float*)d_in[5];
    const float* bb   = (const float*)d_in[6];
    const float* Wo   = (const float*)d_in[7];
    const float* bo   = (const float*)d_in[8];
    const float* lnw  = (const float*)d_in[9];
    const float* rec  = (const float*)d_in[10];
    const float* bb1  = (const float*)d_in[11];
    const float* bb2  = (const float*)d_in[12];
    float* out = (float*)d_out;

    char* w = (char*)d_ws;
    u16* h    = (u16*)w;  w += (size_t)8192 * 512 * 2;
    u16* wcat = (u16*)w;  w += (size_t)1536 * 512 * 2;
    u16* wo   = (u16*)w;  w += (size_t)512 * 512 * 2;
    u16* qh   = (u16*)w;  w += (size_t)8192 * 512 * 2;
    u16* kh   = (u16*)w;  w += (size_t)8192 * 512 * 2;
    u16* vh   = (u16*)w;  w += (size_t)8192 * 512 * 2;
    float* lb1 = (float*)w; w += (size_t)32 * 2048 * 4;
    float* lb2 = (float*)w; w += (size_t)32 * 2048 * 4;
    float* S1  = (float*)w; w += (size_t)1024 * 4096 * 4;
    float* S2  = (float*)w; w += (size_t)1024 * 4096 * 4;
    float* z1  = (float*)w; w += (size_t)1024 * 64 * 4;
    float* z2  = (float*)w; w += (size_t)1024 * 64 * 4;
    float* P1  = (float*)w; w += 4096;
    float* P2  = (float*)w; w += 4096;
    u16* obf   = (u16*)w;   w += (size_t)8192 * 512 * 2;

    k_rmsnorm<<<2048, 256, 0, stream>>>(x, lnw, h);
    k_convw<<<1024, 256, 0, stream>>>(Wq, Wk, Wv, Wo, wcat, wo);
    k_gemm<0><<<dim3(64, 12), 256, 0, stream>>>(h, wcat, 512, mask, qh, kh, vh, nullptr, nullptr, nullptr);
    k_beta<<<2048, 256, 0, stream>>>(h, Wb, bb, rec, bb1, bb2, lb1, lb2);
    k_pass1<<<1024, 256, 0, stream>>>(kh, vh, lb1, lb2, S1, S2, z1, z2, P1, P2);
    k_pass2<<<512, 256, 0, stream>>>(S1, S2, z1, z2, P1, P2);
    k_pass3<<<1024, 256, 0, stream>>>(qh, kh, vh, lb1, lb2, S1, S2, z1, z2, mask, obf);
    k_gemm<1><<<dim3(64, 4), 256, 0, stream>>>(obf, wo, 512, nullptr, nullptr, nullptr, nullptr, x, bo, out);
}

// Round 3
// 118.922 us; speedup vs baseline: 1.4059x; 1.0183x over previous
//
#include <hip/hip_runtime.h>
#include <stdint.h>

typedef unsigned short u16;
typedef short bf16x8 __attribute__((ext_vector_type(8)));
typedef unsigned short u16x8 __attribute__((ext_vector_type(8)));
typedef unsigned short u16x4 __attribute__((ext_vector_type(4)));
typedef float f32x4 __attribute__((ext_vector_type(4)));

#define S_ 2048
#define DM 512
#define DH 64
#define CL 64
#define NCH 32

// swizzled LDS index (u16 elems): row stride 72, XOR col bits 3..5 with row&7
#define SW(r, sc) ((r) * 72 + ((sc) ^ (((r) & 7) << 3)))

__device__ __forceinline__ float b2f(u16 u) { return __uint_as_float(((unsigned)u) << 16); }
__device__ __forceinline__ u16 f2b(float f) {
    unsigned v = __float_as_uint(f);
    unsigned r = v + 0x7fffu + ((v >> 16) & 1u);
    return (u16)(r >> 16);
}
__device__ __forceinline__ float phi_elu(float x) { return x > 0.f ? x + 1.f : __expf(x); }
__device__ __forceinline__ float clip01(float v) { return fminf(fmaxf(v, 0.01f), 0.995f); }

__device__ __forceinline__ void gload16(const u16* g, u16* l) {
    __builtin_amdgcn_global_load_lds((const __attribute__((address_space(1))) void*)g,
                                     (__attribute__((address_space(3))) void*)l, 16, 0, 0);
}

// ---------------- fused RMSNorm + beta/decay ----------------
__global__ __launch_bounds__(256) void k_rb(const float* __restrict__ x, const float* __restrict__ lnw,
                                            const float* __restrict__ Wb, const float* __restrict__ bb,
                                            const float* __restrict__ rec, const float* __restrict__ bb1p,
                                            const float* __restrict__ bb2p, u16* __restrict__ h,
                                            float* __restrict__ lb1, float* __restrict__ lb2) {
    int wave = threadIdx.x >> 6, lane = threadIdx.x & 63;
    int row = blockIdx.x * 4 + wave;
    const float* xr = x + (size_t)row * DM + lane * 8;
    float4 v0 = *(const float4*)xr;
    float4 v1 = *(const float4*)(xr + 4);
    float ss = v0.x * v0.x + v0.y * v0.y + v0.z * v0.z + v0.w * v0.w +
               v1.x * v1.x + v1.y * v1.y + v1.z * v1.z + v1.w * v1.w;
    #pragma unroll
    for (int off = 32; off; off >>= 1) ss += __shfl_xor(ss, off, 64);
    float sc = rsqrtf(ss * (1.f / DM) + 1e-5f);
    const float* wr_ = lnw + lane * 8;
    float4 w0 = *(const float4*)wr_;
    float4 w1 = *(const float4*)(wr_ + 4);
    float hv[8];
    hv[0] = v0.x * sc * w0.x; hv[1] = v0.y * sc * w0.y;
    hv[2] = v0.z * sc * w0.z; hv[3] = v0.w * sc * w0.w;
    hv[4] = v1.x * sc * w1.x; hv[5] = v1.y * sc * w1.y;
    hv[6] = v1.z * sc * w1.z; hv[7] = v1.w * sc * w1.w;
    u16x8 o;
    #pragma unroll
    for (int j = 0; j < 8; j++) o[j] = f2b(hv[j]);
    *(u16x8*)(h + (size_t)row * DM + lane * 8) = o;
    // beta logits: 8 dot products with Wb rows
    float acc[8];
    #pragma unroll
    for (int hd = 0; hd < 8; hd++) {
        const float* wp = Wb + hd * DM + lane * 8;
        float4 a0 = *(const float4*)wp;
        float4 a1 = *(const float4*)(wp + 4);
        acc[hd] = hv[0] * a0.x + hv[1] * a0.y + hv[2] * a0.z + hv[3] * a0.w +
                  hv[4] * a1.x + hv[5] * a1.y + hv[6] * a1.z + hv[7] * a1.w;
    }
    #pragma unroll
    for (int hd = 0; hd < 8; hd++) {
        #pragma unroll
        for (int off = 32; off; off >>= 1) acc[hd] += __shfl_xor(acc[hd], off, 64);
    }
    if (lane == 0) {
        float b1b = clip01(1.f / (1.f + __expf(-bb1p[0])));
        float b2b = clip01(1.f / (1.f + __expf(-bb2p[0])));
        int b = row >> 11, s = row & 2047;
        #pragma unroll
        for (int hd = 0; hd < 8; hd++) {
            float logit = acc[hd] + bb[hd] + rec[hd];
            float beta = 1.f / (1.f + __expf(-logit));
            float bin = clip01(beta);
            float b1 = clip01(b1b * bin);
            float b2 = clip01(b2b * bin);
            size_t o2 = (size_t)((b << 3) + hd) * S_ + s;
            lb1[o2] = log2f(b1);
            lb2[o2] = log2f(b2);
        }
    }
}

// ---------------- weights -> bf16 ----------------
__global__ __launch_bounds__(256) void k_convw(const float* __restrict__ Wq, const float* __restrict__ Wk,
                                               const float* __restrict__ Wv, const float* __restrict__ Wo,
                                               u16* __restrict__ wcat, u16* __restrict__ wo) {
    int idx = blockIdx.x * 256 + threadIdx.x;
    int e0 = idx << 2;
    if (e0 < 1536 * 512) {
        int r = e0 >> 9, ccol = e0 & 511;
        const float* src = (r < 512) ? (Wq + (size_t)r * 512)
                         : (r < 1024) ? (Wk + (size_t)(r - 512) * 512)
                                      : (Wv + (size_t)(r - 1024) * 512);
        float4 v = *(const float4*)(src + ccol);
        u16x4 o = {f2b(v.x), f2b(v.y), f2b(v.z), f2b(v.w)};
        *(u16x4*)(wcat + e0) = o;
    } else {
        int e = e0 - 1536 * 512;
        float4 v = *(const float4*)(Wo + e);
        u16x4 o = {f2b(v.x), f2b(v.y), f2b(v.z), f2b(v.w)};
        *(u16x4*)(wo + e) = o;
    }
}

// ---------------- MFMA bf16 GEMM, m97 structure: global_load_lds width=16 -------------
template<int MODE>
__global__ __launch_bounds__(256) void k_gemm(const u16* __restrict__ A, const u16* __restrict__ Bw, int K,
                                              const float* __restrict__ mask, u16* __restrict__ qh,
                                              u16* __restrict__ kh, u16* __restrict__ vh,
                                              const float* __restrict__ xres, const float* __restrict__ bo,
                                              float* __restrict__ outp) {
    __shared__ u16 As[128 * 32];
    __shared__ u16 Bs[128 * 32];
    int tid = threadIdx.x;
    int lane = tid & 63, w = tid >> 6;
    int wr = w >> 1, wc = w & 1;
    int m0 = blockIdx.x * 128, n0 = blockIdx.y * 128;
    f32x4 acc[4][4] = {};
    int srow = w * 32 + (lane >> 2);
    int skel = (lane & 3) << 3;
    const u16* gA0 = A + (size_t)(m0 + srow) * K + skel;
    const u16* gA1 = gA0 + (size_t)16 * K;
    const u16* gB0 = Bw + (size_t)(n0 + srow) * K + skel;
    const u16* gB1 = gB0 + (size_t)16 * K;
    u16* lA0 = &As[(w * 32) * 32];
    u16* lA1 = &As[(w * 32 + 16) * 32];
    u16* lB0 = &Bs[(w * 32) * 32];
    u16* lB1 = &Bs[(w * 32 + 16) * 32];
    int l15 = lane & 15, kh8 = (lane >> 4) << 3;
    for (int k0 = 0; k0 < K; k0 += 32) {
        if (k0) __syncthreads();
        gload16(gA0 + k0, lA0);
        gload16(gA1 + k0, lA1);
        gload16(gB0 + k0, lB0);
        gload16(gB1 + k0, lB1);
        __syncthreads();
        bf16x8 af[4], bfr[4];
        #pragma unroll
        for (int m = 0; m < 4; m++) af[m] = *(const bf16x8*)&As[(wr * 64 + m * 16 + l15) * 32 + kh8];
        #pragma unroll
        for (int n = 0; n < 4; n++) bfr[n] = *(const bf16x8*)&Bs[(wc * 64 + n * 16 + l15) * 32 + kh8];
        #pragma unroll
        for (int m = 0; m < 4; m++)
            #pragma unroll
            for (int n = 0; n < 4; n++)
                acc[m][n] = __builtin_amdgcn_mfma_f32_16x16x32_bf16(af[m], bfr[n], acc[m][n], 0, 0, 0);
    }
    #pragma unroll
    for (int m = 0; m < 4; m++) {
        int rbase = m0 + wr * 64 + m * 16 + ((lane >> 4) << 2);
        #pragma unroll
        for (int n = 0; n < 4; n++) {
            int col = n0 + wc * 64 + n * 16 + l15;
            #pragma unroll
            for (int r = 0; r < 4; r++) {
                int row = rbase + r;
                float v = acc[m][n][r];
                if constexpr (MODE == 0) {
                    int mat = col >> 9, f = col & 511, hh = f >> 6, j = f & 63;
                    int b = row >> 11, s = row & 2047;
                    size_t di = ((size_t)((b << 3) + hh) * S_ + s) * DH + j;
                    if (mat == 0) qh[di] = f2b(phi_elu(v));
                    else if (mat == 1) kh[di] = f2b(phi_elu(v) * mask[(b << 11) + s]);
                    else vh[di] = f2b(v);
                } else {
                    size_t oi = (size_t)row * DM + col;
                    outp[oi] = v + xres[oi] + bo[col];
                }
            }
        }
    }
}

// ---------------- pass1 (MFMA): per-chunk S1^T,S2^T (bf16), z1,z2, P1,P2 --------------
__global__ __launch_bounds__(256) void k_pass1(const u16* __restrict__ kh, const u16* __restrict__ vh,
                                               const float* __restrict__ lb1, const float* __restrict__ lb2,
                                               u16* __restrict__ S1b, u16* __restrict__ S2b,
                                               float* __restrict__ z1, float* __restrict__ z2,
                                               float* __restrict__ P1, float* __restrict__ P2) {
    __shared__ u16 Kw1[64 * 72];
    __shared__ u16 Kw2[64 * 72];
    __shared__ u16 Vt[64 * 72];
    __shared__ float Ls1[64], Ls2[64];
    int tid = threadIdx.x;
    int bh = blockIdx.x >> 5, c = blockIdx.x & 31;
    int wave = tid >> 6, lane = tid & 63;
    size_t base = ((size_t)bh * S_ + c * CL) * DH;
    if (wave == 0) {
        float v = lb1[(size_t)bh * S_ + c * CL + lane];
        #pragma unroll
        for (int d = 1; d < 64; d <<= 1) { float o = __shfl_up(v, d, 64); if (lane >= d) v += o; }
        Ls1[lane] = v;
    } else if (wave == 1) {
        float v = lb2[(size_t)bh * S_ + c * CL + lane];
        #pragma unroll
        for (int d = 1; d < 64; d <<= 1) { float o = __shfl_up(v, d, 64); if (lane >= d) v += o; }
        Ls2[lane] = v;
    }
    int ss = tid & 63, i0 = (tid >> 6) << 4;
    const u16* kr = kh + base + (size_t)ss * DH + i0;
    u16x8 kk0 = *(const u16x8*)kr;
    u16x8 kk1 = *(const u16x8*)(kr + 8);
    {
        const u16* vr = vh + base + (size_t)ss * DH + i0;
        u16x8 vv0 = *(const u16x8*)vr;
        u16x8 vv1 = *(const u16x8*)(vr + 8);
        #pragma unroll
        for (int j = 0; j < 8; j++) {
            Vt[SW(i0 + j, ss)] = vv0[j];
            Vt[SW(i0 + 8 + j, ss)] = vv1[j];
        }
    }
    __syncthreads();
    float w1 = exp2f(Ls1[63] - Ls1[ss]);
    float w2 = exp2f(Ls2[63] - Ls2[ss]);
    #pragma unroll
    for (int j = 0; j < 8; j++) {
        float k0 = b2f(kk0[j]), k1 = b2f(kk1[j]);
        Kw1[SW(i0 + j, ss)] = f2b(w1 * k0);
        Kw2[SW(i0 + j, ss)] = f2b(w2 * k0);
        Kw1[SW(i0 + 8 + j, ss)] = f2b(w1 * k1);
        Kw2[SW(i0 + 8 + j, ss)] = f2b(w2 * k1);
    }
    if (tid == 0) { P1[blockIdx.x] = exp2f(Ls1[63]); P2[blockIdx.x] = exp2f(Ls2[63]); }
    __syncthreads();
    int l15 = lane & 15, kh8 = (lane >> 4) << 3;
    int j0 = wave << 4;
    bf16x8 vf0 = *(const bf16x8*)&Vt[SW(j0 + l15, kh8)];
    bf16x8 vf1 = *(const bf16x8*)&Vt[SW(j0 + l15, 32 + kh8)];
    f32x4 a1[4], a2[4];
    #pragma unroll
    for (int it = 0; it < 4; it++) { a1[it] = (f32x4){0,0,0,0}; a2[it] = (f32x4){0,0,0,0}; }
    #pragma unroll
    for (int it = 0; it < 4; it++) {
        int ir = (it << 4) + l15;
        bf16x8 b0 = *(const bf16x8*)&Kw1[SW(ir, kh8)];
        bf16x8 b1 = *(const bf16x8*)&Kw1[SW(ir, 32 + kh8)];
        a1[it] = __builtin_amdgcn_mfma_f32_16x16x32_bf16(vf0, b0, a1[it], 0, 0, 0);
        a1[it] = __builtin_amdgcn_mfma_f32_16x16x32_bf16(vf1, b1, a1[it], 0, 0, 0);
        bf16x8 c0 = *(const bf16x8*)&Kw2[SW(ir, kh8)];
        bf16x8 c1 = *(const bf16x8*)&Kw2[SW(ir, 32 + kh8)];
        a2[it] = __builtin_amdgcn_mfma_f32_16x16x32_bf16(vf0, c0, a2[it], 0, 0, 0);
        a2[it] = __builtin_amdgcn_mfma_f32_16x16x32_bf16(vf1, c1, a2[it], 0, 0, 0);
    }
    {
        int iz = tid >> 2, sg = tid & 3;
        u16x8 x0 = *(const u16x8*)&Kw1[SW(iz, sg << 4)];
        u16x8 x1 = *(const u16x8*)&Kw1[SW(iz, (sg << 4) + 8)];
        u16x8 y0 = *(const u16x8*)&Kw2[SW(iz, sg << 4)];
        u16x8 y1 = *(const u16x8*)&Kw2[SW(iz, (sg << 4) + 8)];
        float z1v = 0.f, z2v = 0.f;
        #pragma unroll
        for (int j = 0; j < 8; j++) {
            z1v += b2f(x0[j]) + b2f(x1[j]);
            z2v += b2f(y0[j]) + b2f(y1[j]);
        }
        z1v += __shfl_xor(z1v, 1, 64); z1v += __shfl_xor(z1v, 2, 64);
        z2v += __shfl_xor(z2v, 1, 64); z2v += __shfl_xor(z2v, 2, 64);
        if (sg == 0) {
            z1[(size_t)blockIdx.x * 64 + iz] = z1v;
            z2[(size_t)blockIdx.x * 64 + iz] = z2v;
        }
    }
    int jr0 = j0 + ((lane >> 4) << 2);
    size_t so = (size_t)blockIdx.x * 4096;
    #pragma unroll
    for (int it = 0; it < 4; it++) {
        int ii = (it << 4) + l15;
        #pragma unroll
        for (int r = 0; r < 4; r++) {
            S1b[so + (size_t)(jr0 + r) * 64 + ii] = f2b(a1[it][r]);
            S2b[so + (size_t)(jr0 + r) * 64 + ii] = f2b(a2[it][r]);
        }
    }
}

// ---------------- pass2: cross-chunk scan over bf16 states (f32 carry) ----------------
__global__ __launch_bounds__(256) void k_pass2(u16* __restrict__ S1b, u16* __restrict__ S2b,
                                               float* __restrict__ z1, float* __restrict__ z2,
                                               const float* __restrict__ P1, const float* __restrict__ P2) {
    int bh = blockIdx.x >> 1, part = blockIdx.x & 1;
    int e0 = (part * 256 + threadIdx.x) * 8;
    float c1[8] = {}, c2[8] = {};
    for (int c = 0; c < NCH; c++) {
        int bc = bh * NCH + c;
        size_t idx = (size_t)bc * 4096 + e0;
        u16x8 s1 = *(const u16x8*)&S1b[idx];
        u16x8 s2 = *(const u16x8*)&S2b[idx];
        float p1 = P1[bc], p2 = P2[bc];
        u16x8 o1, o2;
        #pragma unroll
        for (int j = 0; j < 8; j++) {
            o1[j] = f2b(c1[j]); c1[j] = c1[j] * p1 + b2f(s1[j]);
            o2[j] = f2b(c2[j]); c2[j] = c2[j] * p2 + b2f(s2[j]);
        }
        *(u16x8*)&S1b[idx] = o1;
        *(u16x8*)&S2b[idx] = o2;
    }
    if (part == 0 && threadIdx.x < 64) {
        float y1 = 0.f, y2 = 0.f;
        for (int c = 0; c < NCH; c++) {
            int bc = bh * NCH + c;
            size_t zi = (size_t)bc * 64 + threadIdx.x;
            float p1 = P1[bc], p2 = P2[bc];
            float t1 = z1[zi]; z1[zi] = y1; y1 = y1 * p1 + t1;
            float t2 = z2[zi]; z2[zi] = y2; y2 = y2 * p2 + t2;
        }
    }
}

// ---------------- pass3 (MFMA): per-chunk outputs; H frags direct from global ---------
__global__ __launch_bounds__(256) void k_pass3(const u16* __restrict__ qh, const u16* __restrict__ kh,
                                               const u16* __restrict__ vh, const float* __restrict__ lb1,
                                               const float* __restrict__ lb2, const u16* __restrict__ S1b,
                                               const u16* __restrict__ S2b, const float* __restrict__ z1,
                                               const float* __restrict__ z2, const float* __restrict__ mask,
                                               u16* __restrict__ obf) {
    __shared__ u16 Vt[64 * 72];
    __shared__ u16 AWs[64 * 72];
    __shared__ float Ls1[64], Ls2[64], dens[64], qZ1[64], qZ2[64];
    int tid = threadIdx.x;
    int bh = blockIdx.x >> 5, c = blockIdx.x & 31;
    int wave = tid >> 6, lane = tid & 63;
    size_t base = ((size_t)bh * S_ + c * CL) * DH;
    if (wave == 0) {
        float v = lb1[(size_t)bh * S_ + c * CL + lane];
        #pragma unroll
        for (int d = 1; d < 64; d <<= 1) { float o = __shfl_up(v, d, 64); if (lane >= d) v += o; }
        Ls1[lane] = v;
    } else if (wave == 1) {
        float v = lb2[(size_t)bh * S_ + c * CL + lane];
        #pragma unroll
        for (int d = 1; d < 64; d <<= 1) { float o = __shfl_up(v, d, 64); if (lane >= d) v += o; }
        Ls2[lane] = v;
    }
    {   // stage V^T
        int ss = tid & 63, i0 = (tid >> 6) << 4;
        const u16* vr = vh + base + (size_t)ss * DH + i0;
        u16x8 vv0 = *(const u16x8*)vr;
        u16x8 vv1 = *(const u16x8*)(vr + 8);
        #pragma unroll
        for (int j = 0; j < 8; j++) {
            Vt[SW(i0 + j, ss)] = vv0[j];
            Vt[SW(i0 + 8 + j, ss)] = vv1[j];
        }
    }
    {   // qZ dots
        int t = tid >> 2, g = tid & 3;
        const u16* qp = qh + base + (size_t)t * DH + (g << 4);
        u16x8 q0 = *(const u16x8*)qp;
        u16x8 q1 = *(const u16x8*)(qp + 8);
        const float* z1p = z1 + (size_t)blockIdx.x * 64 + (g << 4);
        const float* z2p = z2 + (size_t)blockIdx.x * 64 + (g << 4);
        float az1 = 0.f, az2 = 0.f;
        #pragma unroll
        for (int m = 0; m < 8; m++) {
            float qv0 = b2f(q0[m]), qv1 = b2f(q1[m]);
            az1 += qv0 * z1p[m] + qv1 * z1p[m + 8];
            az2 += qv0 * z2p[m] + qv1 * z2p[m + 8];
        }
        az1 += __shfl_xor(az1, 1, 64); az1 += __shfl_xor(az1, 2, 64);
        az2 += __shfl_xor(az2, 1, 64); az2 += __shfl_xor(az2, 2, 64);
        if (g == 0) { qZ1[t] = az1; qZ2[t] = az2; }
    }
    // A = Q K^T via MFMA (global-direct frags)
    int l15 = lane & 15, kh8 = (lane >> 4) << 3;
    int t0 = wave << 4;
    const u16* qb = qh + base + (size_t)(t0 + l15) * DH;
    bf16x8 qf0 = *(const bf16x8*)(qb + kh8);
    bf16x8 qf1 = *(const bf16x8*)(qb + 32 + kh8);
    f32x4 accA[4];
    #pragma unroll
    for (int st = 0; st < 4; st++) accA[st] = (f32x4){0, 0, 0, 0};
    #pragma unroll
    for (int st = 0; st < 4; st++) {
        const u16* kb = kh + base + (size_t)((st << 4) + l15) * DH;
        bf16x8 kf0 = *(const bf16x8*)(kb + kh8);
        bf16x8 kf1 = *(const bf16x8*)(kb + 32 + kh8);
        accA[st] = __builtin_amdgcn_mfma_f32_16x16x32_bf16(qf0, kf0, accA[st], 0, 0, 0);
        accA[st] = __builtin_amdgcn_mfma_f32_16x16x32_bf16(qf1, kf1, accA[st], 0, 0, 0);
    }
    __syncthreads();
    // W phase
    int trow = t0 + ((lane >> 4) << 2);
    float l1t[4], l2t[4];
    #pragma unroll
    for (int r = 0; r < 4; r++) { l1t[r] = Ls1[trow + r]; l2t[r] = Ls2[trow + r]; }
    float rs[4] = {0.f, 0.f, 0.f, 0.f};
    #pragma unroll
    for (int st = 0; st < 4; st++) {
        int s = (st << 4) + l15;
        float s1 = Ls1[s], s2 = Ls2[s];
        #pragma unroll
        for (int r = 0; r < 4; r++) {
            float w = 0.f;
            if (s <= trow + r) w = exp2f(l1t[r] - s1) + exp2f(l2t[r] - s2);
            u16 awb = f2b(accA[st][r] * w);
            AWs[SW(trow + r, s)] = awb;
            rs[r] += b2f(awb);
        }
    }
    #pragma unroll
    for (int off = 1; off < 16; off <<= 1) {
        #pragma unroll
        for (int r = 0; r < 4; r++) rs[r] += __shfl_xor(rs[r], off, 64);
    }
    if (l15 == 0) {
        #pragma unroll
        for (int r = 0; r < 4; r++) dens[trow + r] = rs[r];
    }
    __syncthreads();
    // O_intra = AW @ V ; cross = Q @ H1, Q @ H2  (H frags read direct from global S^T)
    bf16x8 awf0 = *(const bf16x8*)&AWs[SW(t0 + l15, kh8)];
    bf16x8 awf1 = *(const bf16x8*)&AWs[SW(t0 + l15, 32 + kh8)];
    const u16* h1g = S1b + (size_t)blockIdx.x * 4096;
    const u16* h2g = S2b + (size_t)blockIdx.x * 4096;
    f32x4 accO[4], accC1[4], accC2[4];
    #pragma unroll
    for (int jt = 0; jt < 4; jt++) {
        accO[jt] = (f32x4){0, 0, 0, 0};
        accC1[jt] = (f32x4){0, 0, 0, 0};
        accC2[jt] = (f32x4){0, 0, 0, 0};
    }
    #pragma unroll
    for (int jt = 0; jt < 4; jt++) {
        int jr = (jt << 4) + l15;
        bf16x8 v0 = *(const bf16x8*)&Vt[SW(jr, kh8)];
        bf16x8 v1 = *(const bf16x8*)&Vt[SW(jr, 32 + kh8)];
        accO[jt] = __builtin_amdgcn_mfma_f32_16x16x32_bf16(awf0, v0, accO[jt], 0, 0, 0);
        accO[jt] = __builtin_amdgcn_mfma_f32_16x16x32_bf16(awf1, v1, accO[jt], 0, 0, 0);
        bf16x8 h10 = *(const bf16x8*)(h1g + (size_t)jr * 64 + kh8);
        bf16x8 h11 = *(const bf16x8*)(h1g + (size_t)jr * 64 + 32 + kh8);
        accC1[jt] = __builtin_amdgcn_mfma_f32_16x16x32_bf16(qf0, h10, accC1[jt], 0, 0, 0);
        accC1[jt] = __builtin_amdgcn_mfma_f32_16x16x32_bf16(qf1, h11, accC1[jt], 0, 0, 0);
        bf16x8 h20 = *(const bf16x8*)(h2g + (size_t)jr * 64 + kh8);
        bf16x8 h21 = *(const bf16x8*)(h2g + (size_t)jr * 64 + 32 + kh8);
        accC2[jt] = __builtin_amdgcn_mfma_f32_16x16x32_bf16(qf0, h20, accC2[jt], 0, 0, 0);
        accC2[jt] = __builtin_amdgcn_mfma_f32_16x16x32_bf16(qf1, h21, accC2[jt], 0, 0, 0);
    }
    int b = bh >> 3, hh = bh & 7;
    #pragma unroll
    for (int r = 0; r < 4; r++) {
        int t = trow + r;
        float e1 = exp2f(l1t[r]), e2 = exp2f(l2t[r]);
        float den = dens[t] + e1 * qZ1[t] + e2 * qZ2[t];
        den = fmaxf(den, 1e-6f);
        int sg = (c << 6) + t;
        float mv = mask[(size_t)b * S_ + sg];
        float inv = mv / den;
        u16* op = obf + ((size_t)b * S_ + sg) * DM + hh * DH;
        #pragma unroll
        for (int jt = 0; jt < 4; jt++) {
            float numv = accO[jt][r] + e1 * accC1[jt][r] + e2 * accC2[jt][r];
            op[(jt << 4) + l15] = f2b(numv * inv);
        }
    }
}

extern "C" void kernel_launch(void* const* d_in, const int* in_sizes, int n_in,
                              void* d_out, int out_size, void* d_ws, size_t ws_size,
                              hipStream_t stream) {
    const float* x    = (const float*)d_in[0];
    const float* mask = (const float*)d_in[1];
    const float* Wq   = (const float*)d_in[2];
    const float* Wk   = (const float*)d_in[3];
    const float* Wv   = (const float*)d_in[4];
    const float* Wb   = (const float*)d_in[5];
    const float* bb   = (const float*)d_in[6];
    const float* Wo   = (const float*)d_in[7];
    const float* bo   = (const float*)d_in[8];
    const float* lnw  = (const float*)d_in[9];
    const float* rec  = (const float*)d_in[10];
    const float* bb1  = (const float*)d_in[11];
    const float* bb2  = (const float*)d_in[12];
    float* out = (float*)d_out;

    char* w = (char*)d_ws;
    u16* h    = (u16*)w;  w += (size_t)8192 * 512 * 2;
    u16* wcat = (u16*)w;  w += (size_t)1536 * 512 * 2;
    u16* wo   = (u16*)w;  w += (size_t)512 * 512 * 2;
    u16* qh   = (u16*)w;  w += (size_t)8192 * 512 * 2;
    u16* kh   = (u16*)w;  w += (size_t)8192 * 512 * 2;
    u16* vh   = (u16*)w;  w += (size_t)8192 * 512 * 2;
    float* lb1 = (float*)w; w += (size_t)32 * 2048 * 4;
    float* lb2 = (float*)w; w += (size_t)32 * 2048 * 4;
    u16* S1b  = (u16*)w;  w += (size_t)1024 * 4096 * 2;
    u16* S2b  = (u16*)w;  w += (size_t)1024 * 4096 * 2;
    float* z1  = (float*)w; w += (size_t)1024 * 64 * 4;
    float* z2  = (float*)w; w += (size_t)1024 * 64 * 4;
    float* P1  = (float*)w; w += 4096;
    float* P2  = (float*)w; w += 4096;
    u16* obf   = (u16*)w;   w += (size_t)8192 * 512 * 2;

    k_rb<<<2048, 256, 0, stream>>>(x, lnw, Wb, bb, rec, bb1, bb2, h, lb1, lb2);
    k_convw<<<1024, 256, 0, stream>>>(Wq, Wk, Wv, Wo, wcat, wo);
    k_gemm<0><<<dim3(64, 12), 256, 0, stream>>>(h, wcat, 512, mask, qh, kh, vh, nullptr, nullptr, nullptr);
    k_pass1<<<1024, 256, 0, stream>>>(kh, vh, lb1, lb2, S1b, S2b, z1, z2, P1, P2);
    k_pass2<<<64, 256, 0, stream>>>(S1b, S2b, z1, z2, P1, P2);
    k_pass3<<<1024, 256, 0, stream>>>(qh, kh, vh, lb1, lb2, S1b, S2b, z1, z2, mask, obf);
    k_gemm<1><<<dim3(64, 4), 256, 0, stream>>>(obf, wo, 512, nullptr, nullptr, nullptr, nullptr, x, bo, out);
}

// Round 4
// 112.339 us; speedup vs baseline: 1.4882x; 1.0586x over previous
//
#include <hip/hip_runtime.h>
#include <stdint.h>

typedef unsigned short u16;
typedef short bf16x8 __attribute__((ext_vector_type(8)));
typedef unsigned short u16x8 __attribute__((ext_vector_type(8)));
typedef unsigned short u16x4 __attribute__((ext_vector_type(4)));
typedef float f32x4 __attribute__((ext_vector_type(4)));

#define S_ 2048
#define DM 512
#define DH 64
#define CL 64
#define NCH 32

// swizzled LDS index (u16 elems): row stride 72, XOR col bits 3..5 with row&7
#define SW(r, sc) ((r) * 72 + ((sc) ^ (((r) & 7) << 3)))

__device__ __forceinline__ float b2f(u16 u) { return __uint_as_float(((unsigned)u) << 16); }
__device__ __forceinline__ u16 f2b(float f) {
    unsigned v = __float_as_uint(f);
    unsigned r = v + 0x7fffu + ((v >> 16) & 1u);
    return (u16)(r >> 16);
}
__device__ __forceinline__ float phi_elu(float x) { return x > 0.f ? x + 1.f : __expf(x); }
__device__ __forceinline__ float clip01(float v) { return fminf(fmaxf(v, 0.01f), 0.995f); }

__device__ __forceinline__ void gload16(const u16* g, u16* l) {
    __builtin_amdgcn_global_load_lds((const __attribute__((address_space(1))) void*)g,
                                     (__attribute__((address_space(3))) void*)l, 16, 0, 0);
}

// ---------------- fused RMSNorm + beta/decay ----------------
__global__ __launch_bounds__(256) void k_rb(const float* __restrict__ x, const float* __restrict__ lnw,
                                            const float* __restrict__ Wb, const float* __restrict__ bb,
                                            const float* __restrict__ rec, const float* __restrict__ bb1p,
                                            const float* __restrict__ bb2p, u16* __restrict__ h,
                                            float* __restrict__ lb1, float* __restrict__ lb2) {
    int wave = threadIdx.x >> 6, lane = threadIdx.x & 63;
    int row = blockIdx.x * 4 + wave;
    const float* xr = x + (size_t)row * DM + lane * 8;
    float4 v0 = *(const float4*)xr;
    float4 v1 = *(const float4*)(xr + 4);
    float ss = v0.x * v0.x + v0.y * v0.y + v0.z * v0.z + v0.w * v0.w +
               v1.x * v1.x + v1.y * v1.y + v1.z * v1.z + v1.w * v1.w;
    #pragma unroll
    for (int off = 32; off; off >>= 1) ss += __shfl_xor(ss, off, 64);
    float sc = rsqrtf(ss * (1.f / DM) + 1e-5f);
    const float* wr_ = lnw + lane * 8;
    float4 w0 = *(const float4*)wr_;
    float4 w1 = *(const float4*)(wr_ + 4);
    float hv[8];
    hv[0] = v0.x * sc * w0.x; hv[1] = v0.y * sc * w0.y;
    hv[2] = v0.z * sc * w0.z; hv[3] = v0.w * sc * w0.w;
    hv[4] = v1.x * sc * w1.x; hv[5] = v1.y * sc * w1.y;
    hv[6] = v1.z * sc * w1.z; hv[7] = v1.w * sc * w1.w;
    u16x8 o;
    #pragma unroll
    for (int j = 0; j < 8; j++) o[j] = f2b(hv[j]);
    *(u16x8*)(h + (size_t)row * DM + lane * 8) = o;
    float acc[8];
    #pragma unroll
    for (int hd = 0; hd < 8; hd++) {
        const float* wp = Wb + hd * DM + lane * 8;
        float4 a0 = *(const float4*)wp;
        float4 a1 = *(const float4*)(wp + 4);
        acc[hd] = hv[0] * a0.x + hv[1] * a0.y + hv[2] * a0.z + hv[3] * a0.w +
                  hv[4] * a1.x + hv[5] * a1.y + hv[6] * a1.z + hv[7] * a1.w;
    }
    #pragma unroll
    for (int hd = 0; hd < 8; hd++) {
        #pragma unroll
        for (int off = 32; off; off >>= 1) acc[hd] += __shfl_xor(acc[hd], off, 64);
    }
    if (lane == 0) {
        float b1b = clip01(1.f / (1.f + __expf(-bb1p[0])));
        float b2b = clip01(1.f / (1.f + __expf(-bb2p[0])));
        int b = row >> 11, s = row & 2047;
        #pragma unroll
        for (int hd = 0; hd < 8; hd++) {
            float logit = acc[hd] + bb[hd] + rec[hd];
            float beta = 1.f / (1.f + __expf(-logit));
            float bin = clip01(beta);
            float b1 = clip01(b1b * bin);
            float b2 = clip01(b2b * bin);
            size_t o2 = (size_t)((b << 3) + hd) * S_ + s;
            lb1[o2] = log2f(b1);
            lb2[o2] = log2f(b2);
        }
    }
}

// ---------------- weights -> bf16 ----------------
__global__ __launch_bounds__(256) void k_convw(const float* __restrict__ Wq, const float* __restrict__ Wk,
                                               const float* __restrict__ Wv, const float* __restrict__ Wo,
                                               u16* __restrict__ wcat, u16* __restrict__ wo) {
    int idx = blockIdx.x * 256 + threadIdx.x;
    int e0 = idx << 2;
    if (e0 < 1536 * 512) {
        int r = e0 >> 9, ccol = e0 & 511;
        const float* src = (r < 512) ? (Wq + (size_t)r * 512)
                         : (r < 1024) ? (Wk + (size_t)(r - 512) * 512)
                                      : (Wv + (size_t)(r - 1024) * 512);
        float4 v = *(const float4*)(src + ccol);
        u16x4 o = {f2b(v.x), f2b(v.y), f2b(v.z), f2b(v.w)};
        *(u16x4*)(wcat + e0) = o;
    } else {
        int e = e0 - 1536 * 512;
        float4 v = *(const float4*)(Wo + e);
        u16x4 o = {f2b(v.x), f2b(v.y), f2b(v.z), f2b(v.w)};
        *(u16x4*)(wo + e) = o;
    }
}

// ---------------- MFMA bf16 GEMM, m97 structure + XCD swizzle -------------------------
// NT = N-tile count (gridDim.y); grid total must be %8==0.
template<int MODE, int NT>
__global__ __launch_bounds__(256) void k_gemm(const u16* __restrict__ A, const u16* __restrict__ Bw, int K,
                                              const float* __restrict__ mask, u16* __restrict__ qh,
                                              u16* __restrict__ kh, u16* __restrict__ vh,
                                              const float* __restrict__ xres, const float* __restrict__ bo,
                                              float* __restrict__ outp) {
    __shared__ u16 As[128 * 32];
    __shared__ u16 Bs[128 * 32];
    int tid = threadIdx.x;
    int lane = tid & 63, w = tid >> 6;
    int wr = w >> 1, wc = w & 1;
    // XCD-aware bijective remap: each XCD gets contiguous logical rows -> A panel + full B in its L2
    int hwid = blockIdx.y * gridDim.x + blockIdx.x;
    int nwg = gridDim.x * NT;
    int q8 = nwg >> 3;
    int logical = (hwid & 7) * q8 + (hwid >> 3);
    int mTile = logical / NT, nTile = logical % NT;
    int m0 = mTile * 128, n0 = nTile * 128;
    f32x4 acc[4][4] = {};
    int srow = w * 32 + (lane >> 2);
    int skel = (lane & 3) << 3;
    const u16* gA0 = A + (size_t)(m0 + srow) * K + skel;
    const u16* gA1 = gA0 + (size_t)16 * K;
    const u16* gB0 = Bw + (size_t)(n0 + srow) * K + skel;
    const u16* gB1 = gB0 + (size_t)16 * K;
    u16* lA0 = &As[(w * 32) * 32];
    u16* lA1 = &As[(w * 32 + 16) * 32];
    u16* lB0 = &Bs[(w * 32) * 32];
    u16* lB1 = &Bs[(w * 32 + 16) * 32];
    int l15 = lane & 15, kh8 = (lane >> 4) << 3;
    for (int k0 = 0; k0 < K; k0 += 32) {
        if (k0) __syncthreads();
        gload16(gA0 + k0, lA0);
        gload16(gA1 + k0, lA1);
        gload16(gB0 + k0, lB0);
        gload16(gB1 + k0, lB1);
        __syncthreads();
        bf16x8 af[4], bfr[4];
        #pragma unroll
        for (int m = 0; m < 4; m++) af[m] = *(const bf16x8*)&As[(wr * 64 + m * 16 + l15) * 32 + kh8];
        #pragma unroll
        for (int n = 0; n < 4; n++) bfr[n] = *(const bf16x8*)&Bs[(wc * 64 + n * 16 + l15) * 32 + kh8];
        #pragma unroll
        for (int m = 0; m < 4; m++)
            #pragma unroll
            for (int n = 0; n < 4; n++)
                acc[m][n] = __builtin_amdgcn_mfma_f32_16x16x32_bf16(af[m], bfr[n], acc[m][n], 0, 0, 0);
    }
    #pragma unroll
    for (int m = 0; m < 4; m++) {
        int rbase = m0 + wr * 64 + m * 16 + ((lane >> 4) << 2);
        #pragma unroll
        for (int n = 0; n < 4; n++) {
            int col = n0 + wc * 64 + n * 16 + l15;
            #pragma unroll
            for (int r = 0; r < 4; r++) {
                int row = rbase + r;
                float v = acc[m][n][r];
                if constexpr (MODE == 0) {
                    int mat = col >> 9, f = col & 511, hh = f >> 6, j = f & 63;
                    int b = row >> 11, s = row & 2047;
                    size_t di = ((size_t)((b << 3) + hh) * S_ + s) * DH + j;
                    if (mat == 0) qh[di] = f2b(phi_elu(v));
                    else if (mat == 1) kh[di] = f2b(phi_elu(v) * mask[(b << 11) + s]);
                    else vh[di] = f2b(v);
                } else {
                    size_t oi = (size_t)row * DM + col;
                    outp[oi] = v + xres[oi] + bo[col];
                }
            }
        }
    }
}

// ---------------- pass1 (MFMA): per-chunk S1^T,S2^T (bf16), z1,z2, P1,P2 --------------
__global__ __launch_bounds__(256) void k_pass1(const u16* __restrict__ kh, const u16* __restrict__ vh,
                                               const float* __restrict__ lb1, const float* __restrict__ lb2,
                                               u16* __restrict__ S1b, u16* __restrict__ S2b,
                                               float* __restrict__ z1, float* __restrict__ z2,
                                               float* __restrict__ P1, float* __restrict__ P2) {
    __shared__ u16 Kw1[64 * 72];
    __shared__ u16 Kw2[64 * 72];
    __shared__ u16 Vt[64 * 72];
    __shared__ float Ls1[64], Ls2[64];
    int tid = threadIdx.x;
    int bh = blockIdx.x >> 5, c = blockIdx.x & 31;
    int wave = tid >> 6, lane = tid & 63;
    size_t base = ((size_t)bh * S_ + c * CL) * DH;
    if (wave == 0) {
        float v = lb1[(size_t)bh * S_ + c * CL + lane];
        #pragma unroll
        for (int d = 1; d < 64; d <<= 1) { float o = __shfl_up(v, d, 64); if (lane >= d) v += o; }
        Ls1[lane] = v;
    } else if (wave == 1) {
        float v = lb2[(size_t)bh * S_ + c * CL + lane];
        #pragma unroll
        for (int d = 1; d < 64; d <<= 1) { float o = __shfl_up(v, d, 64); if (lane >= d) v += o; }
        Ls2[lane] = v;
    }
    int ss = tid & 63, i0 = (tid >> 6) << 4;
    const u16* kr = kh + base + (size_t)ss * DH + i0;
    u16x8 kk0 = *(const u16x8*)kr;
    u16x8 kk1 = *(const u16x8*)(kr + 8);
    {
        const u16* vr = vh + base + (size_t)ss * DH + i0;
        u16x8 vv0 = *(const u16x8*)vr;
        u16x8 vv1 = *(const u16x8*)(vr + 8);
        #pragma unroll
        for (int j = 0; j < 8; j++) {
            Vt[SW(i0 + j, ss)] = vv0[j];
            Vt[SW(i0 + 8 + j, ss)] = vv1[j];
        }
    }
    __syncthreads();
    float w1 = exp2f(Ls1[63] - Ls1[ss]);
    float w2 = exp2f(Ls2[63] - Ls2[ss]);
    #pragma unroll
    for (int j = 0; j < 8; j++) {
        float k0 = b2f(kk0[j]), k1 = b2f(kk1[j]);
        Kw1[SW(i0 + j, ss)] = f2b(w1 * k0);
        Kw2[SW(i0 + j, ss)] = f2b(w2 * k0);
        Kw1[SW(i0 + 8 + j, ss)] = f2b(w1 * k1);
        Kw2[SW(i0 + 8 + j, ss)] = f2b(w2 * k1);
    }
    if (tid == 0) { P1[blockIdx.x] = exp2f(Ls1[63]); P2[blockIdx.x] = exp2f(Ls2[63]); }
    __syncthreads();
    int l15 = lane & 15, kh8 = (lane >> 4) << 3;
    int j0 = wave << 4;
    bf16x8 vf0 = *(const bf16x8*)&Vt[SW(j0 + l15, kh8)];
    bf16x8 vf1 = *(const bf16x8*)&Vt[SW(j0 + l15, 32 + kh8)];
    f32x4 a1[4], a2[4];
    #pragma unroll
    for (int it = 0; it < 4; it++) { a1[it] = (f32x4){0,0,0,0}; a2[it] = (f32x4){0,0,0,0}; }
    #pragma unroll
    for (int it = 0; it < 4; it++) {
        int ir = (it << 4) + l15;
        bf16x8 b0 = *(const bf16x8*)&Kw1[SW(ir, kh8)];
        bf16x8 b1 = *(const bf16x8*)&Kw1[SW(ir, 32 + kh8)];
        a1[it] = __builtin_amdgcn_mfma_f32_16x16x32_bf16(vf0, b0, a1[it], 0, 0, 0);
        a1[it] = __builtin_amdgcn_mfma_f32_16x16x32_bf16(vf1, b1, a1[it], 0, 0, 0);
        bf16x8 c0 = *(const bf16x8*)&Kw2[SW(ir, kh8)];
        bf16x8 c1 = *(const bf16x8*)&Kw2[SW(ir, 32 + kh8)];
        a2[it] = __builtin_amdgcn_mfma_f32_16x16x32_bf16(vf0, c0, a2[it], 0, 0, 0);
        a2[it] = __builtin_amdgcn_mfma_f32_16x16x32_bf16(vf1, c1, a2[it], 0, 0, 0);
    }
    {
        int iz = tid >> 2, sg = tid & 3;
        u16x8 x0 = *(const u16x8*)&Kw1[SW(iz, sg << 4)];
        u16x8 x1 = *(const u16x8*)&Kw1[SW(iz, (sg << 4) + 8)];
        u16x8 y0 = *(const u16x8*)&Kw2[SW(iz, sg << 4)];
        u16x8 y1 = *(const u16x8*)&Kw2[SW(iz, (sg << 4) + 8)];
        float z1v = 0.f, z2v = 0.f;
        #pragma unroll
        for (int j = 0; j < 8; j++) {
            z1v += b2f(x0[j]) + b2f(x1[j]);
            z2v += b2f(y0[j]) + b2f(y1[j]);
        }
        z1v += __shfl_xor(z1v, 1, 64); z1v += __shfl_xor(z1v, 2, 64);
        z2v += __shfl_xor(z2v, 1, 64); z2v += __shfl_xor(z2v, 2, 64);
        if (sg == 0) {
            z1[(size_t)blockIdx.x * 64 + iz] = z1v;
            z2[(size_t)blockIdx.x * 64 + iz] = z2v;
        }
    }
    int jr0 = j0 + ((lane >> 4) << 2);
    size_t so = (size_t)blockIdx.x * 4096;
    #pragma unroll
    for (int it = 0; it < 4; it++) {
        int ii = (it << 4) + l15;
        #pragma unroll
        for (int r = 0; r < 4; r++) {
            S1b[so + (size_t)(jr0 + r) * 64 + ii] = f2b(a1[it][r]);
            S2b[so + (size_t)(jr0 + r) * 64 + ii] = f2b(a2[it][r]);
        }
    }
}

// ---------------- pass2: cross-chunk scan, one thread per (bh, elem) ------------------
// blocks 0..511: S-scan (bh = blk/16, elem = (blk%16)*256 + tid)
// blocks 512..519: z-scan (bh = (blk-512)*4 + tid/64, elem = tid%64)
__global__ __launch_bounds__(256) void k_pass2(u16* __restrict__ S1b, u16* __restrict__ S2b,
                                               float* __restrict__ z1, float* __restrict__ z2,
                                               const float* __restrict__ P1, const float* __restrict__ P2) {
    int blk = blockIdx.x;
    if (blk < 512) {
        int bh = blk >> 4;
        int e = ((blk & 15) << 8) + threadIdx.x;
        float c1 = 0.f, c2 = 0.f;
        #pragma unroll 4
        for (int c = 0; c < NCH; c++) {
            int bc = bh * NCH + c;
            size_t idx = (size_t)bc * 4096 + e;
            float p1 = P1[bc], p2 = P2[bc];
            float t1 = b2f(S1b[idx]); S1b[idx] = f2b(c1); c1 = c1 * p1 + t1;
            float t2 = b2f(S2b[idx]); S2b[idx] = f2b(c2); c2 = c2 * p2 + t2;
        }
    } else {
        int bh = ((blk - 512) << 2) + (threadIdx.x >> 6);
        int e = threadIdx.x & 63;
        float y1 = 0.f, y2 = 0.f;
        #pragma unroll 4
        for (int c = 0; c < NCH; c++) {
            int bc = bh * NCH + c;
            size_t zi = (size_t)bc * 64 + e;
            float p1 = P1[bc], p2 = P2[bc];
            float t1 = z1[zi]; z1[zi] = y1; y1 = y1 * p1 + t1;
            float t2 = z2[zi]; z2[zi] = y2; y2 = y2 * p2 + t2;
        }
    }
}

// ---------------- pass3 (MFMA): per-chunk outputs; H frags direct from global ---------
__global__ __launch_bounds__(256) void k_pass3(const u16* __restrict__ qh, const u16* __restrict__ kh,
                                               const u16* __restrict__ vh, const float* __restrict__ lb1,
                                               const float* __restrict__ lb2, const u16* __restrict__ S1b,
                                               const u16* __restrict__ S2b, const float* __restrict__ z1,
                                               const float* __restrict__ z2, const float* __restrict__ mask,
                                               u16* __restrict__ obf) {
    __shared__ u16 Vt[64 * 72];
    __shared__ u16 AWs[64 * 72];
    __shared__ float Ls1[64], Ls2[64], dens[64], qZ1[64], qZ2[64];
    int tid = threadIdx.x;
    int bh = blockIdx.x >> 5, c = blockIdx.x & 31;
    int wave = tid >> 6, lane = tid & 63;
    size_t base = ((size_t)bh * S_ + c * CL) * DH;
    if (wave == 0) {
        float v = lb1[(size_t)bh * S_ + c * CL + lane];
        #pragma unroll
        for (int d = 1; d < 64; d <<= 1) { float o = __shfl_up(v, d, 64); if (lane >= d) v += o; }
        Ls1[lane] = v;
    } else if (wave == 1) {
        float v = lb2[(size_t)bh * S_ + c * CL + lane];
        #pragma unroll
        for (int d = 1; d < 64; d <<= 1) { float o = __shfl_up(v, d, 64); if (lane >= d) v += o; }
        Ls2[lane] = v;
    }
    {   // stage V^T
        int ss = tid & 63, i0 = (tid >> 6) << 4;
        const u16* vr = vh + base + (size_t)ss * DH + i0;
        u16x8 vv0 = *(const u16x8*)vr;
        u16x8 vv1 = *(const u16x8*)(vr + 8);
        #pragma unroll
        for (int j = 0; j < 8; j++) {
            Vt[SW(i0 + j, ss)] = vv0[j];
            Vt[SW(i0 + 8 + j, ss)] = vv1[j];
        }
    }
    {   // qZ dots
        int t = tid >> 2, g = tid & 3;
        const u16* qp = qh + base + (size_t)t * DH + (g << 4);
        u16x8 q0 = *(const u16x8*)qp;
        u16x8 q1 = *(const u16x8*)(qp + 8);
        const float* z1p = z1 + (size_t)blockIdx.x * 64 + (g << 4);
        const float* z2p = z2 + (size_t)blockIdx.x * 64 + (g << 4);
        float az1 = 0.f, az2 = 0.f;
        #pragma unroll
        for (int m = 0; m < 8; m++) {
            float qv0 = b2f(q0[m]), qv1 = b2f(q1[m]);
            az1 += qv0 * z1p[m] + qv1 * z1p[m + 8];
            az2 += qv0 * z2p[m] + qv1 * z2p[m + 8];
        }
        az1 += __shfl_xor(az1, 1, 64); az1 += __shfl_xor(az1, 2, 64);
        az2 += __shfl_xor(az2, 1, 64); az2 += __shfl_xor(az2, 2, 64);
        if (g == 0) { qZ1[t] = az1; qZ2[t] = az2; }
    }
    int l15 = lane & 15, kh8 = (lane >> 4) << 3;
    int t0 = wave << 4;
    const u16* qb = qh + base + (size_t)(t0 + l15) * DH;
    bf16x8 qf0 = *(const bf16x8*)(qb + kh8);
    bf16x8 qf1 = *(const bf16x8*)(qb + 32 + kh8);
    f32x4 accA[4];
    #pragma unroll
    for (int st = 0; st < 4; st++) accA[st] = (f32x4){0, 0, 0, 0};
    #pragma unroll
    for (int st = 0; st < 4; st++) {
        const u16* kb = kh + base + (size_t)((st << 4) + l15) * DH;
        bf16x8 kf0 = *(const bf16x8*)(kb + kh8);
        bf16x8 kf1 = *(const bf16x8*)(kb + 32 + kh8);
        accA[st] = __builtin_amdgcn_mfma_f32_16x16x32_bf16(qf0, kf0, accA[st], 0, 0, 0);
        accA[st] = __builtin_amdgcn_mfma_f32_16x16x32_bf16(qf1, kf1, accA[st], 0, 0, 0);
    }
    __syncthreads();
    int trow = t0 + ((lane >> 4) << 2);
    float l1t[4], l2t[4];
    #pragma unroll
    for (int r = 0; r < 4; r++) { l1t[r] = Ls1[trow + r]; l2t[r] = Ls2[trow + r]; }
    float rs[4] = {0.f, 0.f, 0.f, 0.f};
    #pragma unroll
    for (int st = 0; st < 4; st++) {
        int s = (st << 4) + l15;
        float s1 = Ls1[s], s2 = Ls2[s];
        #pragma unroll
        for (int r = 0; r < 4; r++) {
            float w = 0.f;
            if (s <= trow + r) w = exp2f(l1t[r] - s1) + exp2f(l2t[r] - s2);
            u16 awb = f2b(accA[st][r] * w);
            AWs[SW(trow + r, s)] = awb;
            rs[r] += b2f(awb);
        }
    }
    #pragma unroll
    for (int off = 1; off < 16; off <<= 1) {
        #pragma unroll
        for (int r = 0; r < 4; r++) rs[r] += __shfl_xor(rs[r], off, 64);
    }
    if (l15 == 0) {
        #pragma unroll
        for (int r = 0; r < 4; r++) dens[trow + r] = rs[r];
    }
    __syncthreads();
    bf16x8 awf0 = *(const bf16x8*)&AWs[SW(t0 + l15, kh8)];
    bf16x8 awf1 = *(const bf16x8*)&AWs[SW(t0 + l15, 32 + kh8)];
    const u16* h1g = S1b + (size_t)blockIdx.x * 4096;
    const u16* h2g = S2b + (size_t)blockIdx.x * 4096;
    f32x4 accO[4], accC1[4], accC2[4];
    #pragma unroll
    for (int jt = 0; jt < 4; jt++) {
        accO[jt] = (f32x4){0, 0, 0, 0};
        accC1[jt] = (f32x4){0, 0, 0, 0};
        accC2[jt] = (f32x4){0, 0, 0, 0};
    }
    #pragma unroll
    for (int jt = 0; jt < 4; jt++) {
        int jr = (jt << 4) + l15;
        bf16x8 v0 = *(const bf16x8*)&Vt[SW(jr, kh8)];
        bf16x8 v1 = *(const bf16x8*)&Vt[SW(jr, 32 + kh8)];
        accO[jt] = __builtin_amdgcn_mfma_f32_16x16x32_bf16(awf0, v0, accO[jt], 0, 0, 0);
        accO[jt] = __builtin_amdgcn_mfma_f32_16x16x32_bf16(awf1, v1, accO[jt], 0, 0, 0);
        bf16x8 h10 = *(const bf16x8*)(h1g + (size_t)jr * 64 + kh8);
        bf16x8 h11 = *(const bf16x8*)(h1g + (size_t)jr * 64 + 32 + kh8);
        accC1[jt] = __builtin_amdgcn_mfma_f32_16x16x32_bf16(qf0, h10, accC1[jt], 0, 0, 0);
        accC1[jt] = __builtin_amdgcn_mfma_f32_16x16x32_bf16(qf1, h11, accC1[jt], 0, 0, 0);
        bf16x8 h20 = *(const bf16x8*)(h2g + (size_t)jr * 64 + kh8);
        bf16x8 h21 = *(const bf16x8*)(h2g + (size_t)jr * 64 + 32 + kh8);
        accC2[jt] = __builtin_amdgcn_mfma_f32_16x16x32_bf16(qf0, h20, accC2[jt], 0, 0, 0);
        accC2[jt] = __builtin_amdgcn_mfma_f32_16x16x32_bf16(qf1, h21, accC2[jt], 0, 0, 0);
    }
    int b = bh >> 3, hh = bh & 7;
    #pragma unroll
    for (int r = 0; r < 4; r++) {
        int t = trow + r;
        float e1 = exp2f(l1t[r]), e2 = exp2f(l2t[r]);
        float den = dens[t] + e1 * qZ1[t] + e2 * qZ2[t];
        den = fmaxf(den, 1e-6f);
        int sg = (c << 6) + t;
        float mv = mask[(size_t)b * S_ + sg];
        float inv = mv / den;
        u16* op = obf + ((size_t)b * S_ + sg) * DM + hh * DH;
        #pragma unroll
        for (int jt = 0; jt < 4; jt++) {
            float numv = accO[jt][r] + e1 * accC1[jt][r] + e2 * accC2[jt][r];
            op[(jt << 4) + l15] = f2b(numv * inv);
        }
    }
}

extern "C" void kernel_launch(void* const* d_in, const int* in_sizes, int n_in,
                              void* d_out, int out_size, void* d_ws, size_t ws_size,
                              hipStream_t stream) {
    const float* x    = (const float*)d_in[0];
    const float* mask = (const float*)d_in[1];
    const float* Wq   = (const float*)d_in[2];
    const float* Wk   = (const float*)d_in[3];
    const float* Wv   = (const float*)d_in[4];
    const float* Wb   = (const float*)d_in[5];
    const float* bb   = (const float*)d_in[6];
    const float* Wo   = (const float*)d_in[7];
    const float* bo   = (const float*)d_in[8];
    const float* lnw  = (const float*)d_in[9];
    const float* rec  = (const float*)d_in[10];
    const float* bb1  = (const float*)d_in[11];
    const float* bb2  = (const float*)d_in[12];
    float* out = (float*)d_out;

    char* w = (char*)d_ws;
    u16* h    = (u16*)w;  w += (size_t)8192 * 512 * 2;
    u16* wcat = (u16*)w;  w += (size_t)1536 * 512 * 2;
    u16* wo   = (u16*)w;  w += (size_t)512 * 512 * 2;
    u16* qh   = (u16*)w;  w += (size_t)8192 * 512 * 2;
    u16* kh   = (u16*)w;  w += (size_t)8192 * 512 * 2;
    u16* vh   = (u16*)w;  w += (size_t)8192 * 512 * 2;
    float* lb1 = (float*)w; w += (size_t)32 * 2048 * 4;
    float* lb2 = (float*)w; w += (size_t)32 * 2048 * 4;
    u16* S1b  = (u16*)w;  w += (size_t)1024 * 4096 * 2;
    u16* S2b  = (u16*)w;  w += (size_t)1024 * 4096 * 2;
    float* z1  = (float*)w; w += (size_t)1024 * 64 * 4;
    float* z2  = (float*)w; w += (size_t)1024 * 64 * 4;
    float* P1  = (float*)w; w += 4096;
    float* P2  = (float*)w; w += 4096;
    u16* obf   = (u16*)w;   w += (size_t)8192 * 512 * 2;

    k_rb<<<2048, 256, 0, stream>>>(x, lnw, Wb, bb, rec, bb1, bb2, h, lb1, lb2);
    k_convw<<<1024, 256, 0, stream>>>(Wq, Wk, Wv, Wo, wcat, wo);
    k_gemm<0, 12><<<dim3(64, 12), 256, 0, stream>>>(h, wcat, 512, mask, qh, kh, vh, nullptr, nullptr, nullptr);
    k_pass1<<<1024, 256, 0, stream>>>(kh, vh, lb1, lb2, S1b, S2b, z1, z2, P1, P2);
    k_pass2<<<520, 256, 0, stream>>>(S1b, S2b, z1, z2, P1, P2);
    k_pass3<<<1024, 256, 0, stream>>>(qh, kh, vh, lb1, lb2, S1b, S2b, z1, z2, mask, obf);
    k_gemm<1, 4><<<dim3(64, 4), 256, 0, stream>>>(obf, wo, 512, nullptr, nullptr, nullptr, nullptr, x, bo, out);
}

// Round 5
// 104.962 us; speedup vs baseline: 1.5928x; 1.0703x over previous
//
#include <hip/hip_runtime.h>
#include <stdint.h>

typedef unsigned short u16;
typedef short bf16x8 __attribute__((ext_vector_type(8)));
typedef unsigned short u16x8 __attribute__((ext_vector_type(8)));
typedef unsigned short u16x4 __attribute__((ext_vector_type(4)));
typedef float f32x4 __attribute__((ext_vector_type(4)));

#define S_ 2048
#define DM 512
#define DH 64
#define CL 64
#define NCH 32

// swizzled LDS index (u16 elems): row stride 72, XOR col bits 3..5 with row&7
#define SW(r, sc) ((r) * 72 + ((sc) ^ (((r) & 7) << 3)))

__device__ __forceinline__ float b2f(u16 u) { return __uint_as_float(((unsigned)u) << 16); }
__device__ __forceinline__ u16 f2b(float f) {
    unsigned v = __float_as_uint(f);
    unsigned r = v + 0x7fffu + ((v >> 16) & 1u);
    return (u16)(r >> 16);
}
__device__ __forceinline__ float phi_elu(float x) { return x > 0.f ? x + 1.f : __expf(x); }
__device__ __forceinline__ float clip01(float v) { return fminf(fmaxf(v, 0.01f), 0.995f); }

__device__ __forceinline__ void gload16(const u16* g, u16* l) {
    __builtin_amdgcn_global_load_lds((const __attribute__((address_space(1))) void*)g,
                                     (__attribute__((address_space(3))) void*)l, 16, 0, 0);
}

// ---------------- fused RMSNorm+beta (blocks 0..2047) and weight-convert (2048..3071) --
__global__ __launch_bounds__(256) void k_rbw(const float* __restrict__ x, const float* __restrict__ lnw,
                                             const float* __restrict__ Wb, const float* __restrict__ bb,
                                             const float* __restrict__ rec, const float* __restrict__ bb1p,
                                             const float* __restrict__ bb2p, u16* __restrict__ h,
                                             float* __restrict__ lb1, float* __restrict__ lb2,
                                             const float* __restrict__ Wq, const float* __restrict__ Wk,
                                             const float* __restrict__ Wv, const float* __restrict__ Wo,
                                             u16* __restrict__ wcat, u16* __restrict__ wo) {
    if (blockIdx.x >= 2048) {
        int idx = (blockIdx.x - 2048) * 256 + threadIdx.x;
        int e0 = idx << 2;
        if (e0 < 1536 * 512) {
            int r = e0 >> 9, ccol = e0 & 511;
            const float* src = (r < 512) ? (Wq + (size_t)r * 512)
                             : (r < 1024) ? (Wk + (size_t)(r - 512) * 512)
                                          : (Wv + (size_t)(r - 1024) * 512);
            float4 v = *(const float4*)(src + ccol);
            u16x4 o = {f2b(v.x), f2b(v.y), f2b(v.z), f2b(v.w)};
            *(u16x4*)(wcat + e0) = o;
        } else {
            int e = e0 - 1536 * 512;
            float4 v = *(const float4*)(Wo + e);
            u16x4 o = {f2b(v.x), f2b(v.y), f2b(v.z), f2b(v.w)};
            *(u16x4*)(wo + e) = o;
        }
        return;
    }
    int wave = threadIdx.x >> 6, lane = threadIdx.x & 63;
    int row = blockIdx.x * 4 + wave;
    const float* xr = x + (size_t)row * DM + lane * 8;
    float4 v0 = *(const float4*)xr;
    float4 v1 = *(const float4*)(xr + 4);
    float ss = v0.x * v0.x + v0.y * v0.y + v0.z * v0.z + v0.w * v0.w +
               v1.x * v1.x + v1.y * v1.y + v1.z * v1.z + v1.w * v1.w;
    #pragma unroll
    for (int off = 32; off; off >>= 1) ss += __shfl_xor(ss, off, 64);
    float sc = rsqrtf(ss * (1.f / DM) + 1e-5f);
    const float* wr_ = lnw + lane * 8;
    float4 w0 = *(const float4*)wr_;
    float4 w1 = *(const float4*)(wr_ + 4);
    float hv[8];
    hv[0] = v0.x * sc * w0.x; hv[1] = v0.y * sc * w0.y;
    hv[2] = v0.z * sc * w0.z; hv[3] = v0.w * sc * w0.w;
    hv[4] = v1.x * sc * w1.x; hv[5] = v1.y * sc * w1.y;
    hv[6] = v1.z * sc * w1.z; hv[7] = v1.w * sc * w1.w;
    u16x8 o;
    #pragma unroll
    for (int j = 0; j < 8; j++) o[j] = f2b(hv[j]);
    *(u16x8*)(h + (size_t)row * DM + lane * 8) = o;
    float acc[8];
    #pragma unroll
    for (int hd = 0; hd < 8; hd++) {
        const float* wp = Wb + hd * DM + lane * 8;
        float4 a0 = *(const float4*)wp;
        float4 a1 = *(const float4*)(wp + 4);
        acc[hd] = hv[0] * a0.x + hv[1] * a0.y + hv[2] * a0.z + hv[3] * a0.w +
                  hv[4] * a1.x + hv[5] * a1.y + hv[6] * a1.z + hv[7] * a1.w;
    }
    #pragma unroll
    for (int hd = 0; hd < 8; hd++) {
        #pragma unroll
        for (int off = 32; off; off >>= 1) acc[hd] += __shfl_xor(acc[hd], off, 64);
    }
    if (lane == 0) {
        float b1b = clip01(1.f / (1.f + __expf(-bb1p[0])));
        float b2b = clip01(1.f / (1.f + __expf(-bb2p[0])));
        int b = row >> 11, s = row & 2047;
        #pragma unroll
        for (int hd = 0; hd < 8; hd++) {
            float logit = acc[hd] + bb[hd] + rec[hd];
            float beta = 1.f / (1.f + __expf(-logit));
            float bin = clip01(beta);
            float b1 = clip01(b1b * bin);
            float b2 = clip01(b2b * bin);
            size_t o2 = (size_t)((b << 3) + hd) * S_ + s;
            lb1[o2] = log2f(b1);
            lb2[o2] = log2f(b2);
        }
    }
}

// ---------------- MFMA bf16 GEMM, m97 staging + XCD swizzle + LDS-bounce epilogue -----
template<int MODE, int NT>
__global__ __launch_bounds__(256) void k_gemm(const u16* __restrict__ A, const u16* __restrict__ Bw, int K,
                                              const float* __restrict__ mask, u16* __restrict__ qh,
                                              u16* __restrict__ kh, u16* __restrict__ vh,
                                              const float* __restrict__ xres, const float* __restrict__ bo,
                                              float* __restrict__ outp) {
    __shared__ u16 SH[8960];   // staging: [0..8191]; epilogue bounce: up to 8960 u16 / 4352 f32
    u16* As = SH;
    u16* Bs = SH + 4096;
    int tid = threadIdx.x;
    int lane = tid & 63, w = tid >> 6;
    int wr = w >> 1, wc = w & 1;
    int hwid = blockIdx.y * gridDim.x + blockIdx.x;
    int nwg = gridDim.x * NT;
    int q8 = nwg >> 3;
    int logical = (hwid & 7) * q8 + (hwid >> 3);
    int mTile = logical / NT, nTile = logical % NT;
    int m0 = mTile * 128, n0 = nTile * 128;
    f32x4 acc[4][4] = {};
    int srow = w * 32 + (lane >> 2);
    int skel = (lane & 3) << 3;
    const u16* gA0 = A + (size_t)(m0 + srow) * K + skel;
    const u16* gA1 = gA0 + (size_t)16 * K;
    const u16* gB0 = Bw + (size_t)(n0 + srow) * K + skel;
    const u16* gB1 = gB0 + (size_t)16 * K;
    u16* lA0 = &As[(w * 32) * 32];
    u16* lA1 = &As[(w * 32 + 16) * 32];
    u16* lB0 = &Bs[(w * 32) * 32];
    u16* lB1 = &Bs[(w * 32 + 16) * 32];
    int l15 = lane & 15, kh8 = (lane >> 4) << 3;
    for (int k0 = 0; k0 < K; k0 += 32) {
        if (k0) __syncthreads();
        gload16(gA0 + k0, lA0);
        gload16(gA1 + k0, lA1);
        gload16(gB0 + k0, lB0);
        gload16(gB1 + k0, lB1);
        __syncthreads();
        bf16x8 af[4], bfr[4];
        #pragma unroll
        for (int m = 0; m < 4; m++) af[m] = *(const bf16x8*)&As[(wr * 64 + m * 16 + l15) * 32 + kh8];
        #pragma unroll
        for (int n = 0; n < 4; n++) bfr[n] = *(const bf16x8*)&Bs[(wc * 64 + n * 16 + l15) * 32 + kh8];
        #pragma unroll
        for (int m = 0; m < 4; m++)
            #pragma unroll
            for (int n = 0; n < 4; n++)
                acc[m][n] = __builtin_amdgcn_mfma_f32_16x16x32_bf16(af[m], bfr[n], acc[m][n], 0, 0, 0);
    }
    __syncthreads();   // staging region dead; reuse SH for epilogue bounce
    if constexpr (MODE == 0) {
        int mat = n0 >> 9;
        int cb = n0 & 511;
        u16* basep = (mat == 0) ? qh : (mat == 1) ? kh : vh;
        #pragma unroll
        for (int P = 0; P < 2; P++) {
            if (wr == P) {
                #pragma unroll
                for (int m = 0; m < 4; m++)
                    #pragma unroll
                    for (int n = 0; n < 4; n++)
                        #pragma unroll
                        for (int r = 0; r < 4; r++) {
                            int rl = m * 16 + ((lane >> 4) << 2) + r;
                            int colL = wc * 64 + n * 16 + l15;
                            SH[rl * 140 + colL] = f2b(acc[m][n][r]);
                        }
            }
            __syncthreads();
            {
                int rl = tid >> 2;
                int gr = m0 + P * 64 + rl;
                int b = gr >> 11, s = gr & 2047;
                float mv = (mat == 1) ? mask[(b << 11) + s] : 1.f;
                #pragma unroll
                for (int cc = 0; cc < 4; cc++) {
                    int cl = ((tid & 3) << 5) + (cc << 3);
                    u16x8 vv = *(const u16x8*)&SH[rl * 140 + cl];
                    int f = cb + cl;
                    int hh = f >> 6, j = f & 63;
                    u16* dst = basep + ((size_t)(b * 8 + hh) * S_ + s) * DH + j;
                    if (mat == 2) {
                        *(u16x8*)dst = vv;
                    } else {
                        u16x8 ov;
                        #pragma unroll
                        for (int e = 0; e < 8; e++) {
                            float v = b2f(vv[e]);
                            ov[e] = f2b(phi_elu(v) * mv);
                        }
                        *(u16x8*)dst = ov;
                    }
                }
            }
            __syncthreads();
        }
    } else {
        float* SF = (float*)SH;
        #pragma unroll
        for (int Pq = 0; Pq < 4; Pq++) {
            if (wr == (Pq >> 1)) {
                int mbase = (Pq & 1) * 2;
                #pragma unroll
                for (int mm = 0; mm < 2; mm++)
                    #pragma unroll
                    for (int n = 0; n < 4; n++)
                        #pragma unroll
                        for (int r = 0; r < 4; r++) {
                            int rl = mm * 16 + ((lane >> 4) << 2) + r;
                            int colL = wc * 64 + n * 16 + l15;
                            SF[rl * 136 + colL] = acc[mbase + mm][n][r];
                        }
            }
            __syncthreads();
            {
                int rl = tid >> 3;
                int gr = m0 + Pq * 32 + rl;
                int col0 = (tid & 7) << 4;
                const float* xr = xres + (size_t)gr * DM + n0 + col0;
                float* orow = outp + (size_t)gr * DM + n0 + col0;
                #pragma unroll
                for (int cc = 0; cc < 4; cc++) {
                    int cl = col0 + (cc << 2);
                    float4 v = *(const float4*)&SF[rl * 136 + cl];
                    float4 xv = *(const float4*)(xr + (cc << 2));
                    float4 bv = *(const float4*)(bo + n0 + cl);
                    float4 ov = {v.x + xv.x + bv.x, v.y + xv.y + bv.y,
                                 v.z + xv.z + bv.z, v.w + xv.w + bv.w};
                    *(float4*)(orow + (cc << 2)) = ov;
                }
            }
            __syncthreads();
        }
    }
}

// ---------------- pass1 (MFMA): per-chunk S1^T,S2^T (bf16), z1,z2, P1,P2 --------------
__global__ __launch_bounds__(256) void k_pass1(const u16* __restrict__ kh, const u16* __restrict__ vh,
                                               const float* __restrict__ lb1, const float* __restrict__ lb2,
                                               u16* __restrict__ S1b, u16* __restrict__ S2b,
                                               float* __restrict__ z1, float* __restrict__ z2,
                                               float* __restrict__ P1, float* __restrict__ P2) {
    __shared__ u16 Kw1[64 * 72];
    __shared__ u16 Kw2[64 * 72];
    __shared__ u16 Vt[64 * 72];
    __shared__ float Ls1[64], Ls2[64];
    int tid = threadIdx.x;
    int bh = blockIdx.x >> 5, c = blockIdx.x & 31;
    int wave = tid >> 6, lane = tid & 63;
    size_t base = ((size_t)bh * S_ + c * CL) * DH;
    if (wave == 0) {
        float v = lb1[(size_t)bh * S_ + c * CL + lane];
        #pragma unroll
        for (int d = 1; d < 64; d <<= 1) { float o = __shfl_up(v, d, 64); if (lane >= d) v += o; }
        Ls1[lane] = v;
    } else if (wave == 1) {
        float v = lb2[(size_t)bh * S_ + c * CL + lane];
        #pragma unroll
        for (int d = 1; d < 64; d <<= 1) { float o = __shfl_up(v, d, 64); if (lane >= d) v += o; }
        Ls2[lane] = v;
    }
    int ss = tid & 63, i0 = (tid >> 6) << 4;
    const u16* kr = kh + base + (size_t)ss * DH + i0;
    u16x8 kk0 = *(const u16x8*)kr;
    u16x8 kk1 = *(const u16x8*)(kr + 8);
    {
        const u16* vr = vh + base + (size_t)ss * DH + i0;
        u16x8 vv0 = *(const u16x8*)vr;
        u16x8 vv1 = *(const u16x8*)(vr + 8);
        #pragma unroll
        for (int j = 0; j < 8; j++) {
            Vt[SW(i0 + j, ss)] = vv0[j];
            Vt[SW(i0 + 8 + j, ss)] = vv1[j];
        }
    }
    __syncthreads();
    float w1 = exp2f(Ls1[63] - Ls1[ss]);
    float w2 = exp2f(Ls2[63] - Ls2[ss]);
    #pragma unroll
    for (int j = 0; j < 8; j++) {
        float k0 = b2f(kk0[j]), k1 = b2f(kk1[j]);
        Kw1[SW(i0 + j, ss)] = f2b(w1 * k0);
        Kw2[SW(i0 + j, ss)] = f2b(w2 * k0);
        Kw1[SW(i0 + 8 + j, ss)] = f2b(w1 * k1);
        Kw2[SW(i0 + 8 + j, ss)] = f2b(w2 * k1);
    }
    if (tid == 0) { P1[blockIdx.x] = exp2f(Ls1[63]); P2[blockIdx.x] = exp2f(Ls2[63]); }
    __syncthreads();
    int l15 = lane & 15, kh8 = (lane >> 4) << 3;
    int j0 = wave << 4;
    bf16x8 vf0 = *(const bf16x8*)&Vt[SW(j0 + l15, kh8)];
    bf16x8 vf1 = *(const bf16x8*)&Vt[SW(j0 + l15, 32 + kh8)];
    f32x4 a1[4], a2[4];
    #pragma unroll
    for (int it = 0; it < 4; it++) { a1[it] = (f32x4){0,0,0,0}; a2[it] = (f32x4){0,0,0,0}; }
    #pragma unroll
    for (int it = 0; it < 4; it++) {
        int ir = (it << 4) + l15;
        bf16x8 b0 = *(const bf16x8*)&Kw1[SW(ir, kh8)];
        bf16x8 b1 = *(const bf16x8*)&Kw1[SW(ir, 32 + kh8)];
        a1[it] = __builtin_amdgcn_mfma_f32_16x16x32_bf16(vf0, b0, a1[it], 0, 0, 0);
        a1[it] = __builtin_amdgcn_mfma_f32_16x16x32_bf16(vf1, b1, a1[it], 0, 0, 0);
        bf16x8 c0 = *(const bf16x8*)&Kw2[SW(ir, kh8)];
        bf16x8 c1 = *(const bf16x8*)&Kw2[SW(ir, 32 + kh8)];
        a2[it] = __builtin_amdgcn_mfma_f32_16x16x32_bf16(vf0, c0, a2[it], 0, 0, 0);
        a2[it] = __builtin_amdgcn_mfma_f32_16x16x32_bf16(vf1, c1, a2[it], 0, 0, 0);
    }
    {
        int iz = tid >> 2, sg = tid & 3;
        u16x8 x0 = *(const u16x8*)&Kw1[SW(iz, sg << 4)];
        u16x8 x1 = *(const u16x8*)&Kw1[SW(iz, (sg << 4) + 8)];
        u16x8 y0 = *(const u16x8*)&Kw2[SW(iz, sg << 4)];
        u16x8 y1 = *(const u16x8*)&Kw2[SW(iz, (sg << 4) + 8)];
        float z1v = 0.f, z2v = 0.f;
        #pragma unroll
        for (int j = 0; j < 8; j++) {
            z1v += b2f(x0[j]) + b2f(x1[j]);
            z2v += b2f(y0[j]) + b2f(y1[j]);
        }
        z1v += __shfl_xor(z1v, 1, 64); z1v += __shfl_xor(z1v, 2, 64);
        z2v += __shfl_xor(z2v, 1, 64); z2v += __shfl_xor(z2v, 2, 64);
        if (sg == 0) {
            z1[(size_t)blockIdx.x * 64 + iz] = z1v;
            z2[(size_t)blockIdx.x * 64 + iz] = z2v;
        }
    }
    int jr0 = j0 + ((lane >> 4) << 2);
    size_t so = (size_t)blockIdx.x * 4096;
    #pragma unroll
    for (int it = 0; it < 4; it++) {
        int ii = (it << 4) + l15;
        #pragma unroll
        for (int r = 0; r < 4; r++) {
            S1b[so + (size_t)(jr0 + r) * 64 + ii] = f2b(a1[it][r]);
            S2b[so + (size_t)(jr0 + r) * 64 + ii] = f2b(a2[it][r]);
        }
    }
}

// ---------------- pass2: cross-chunk scan, one thread per (bh, elem) ------------------
__global__ __launch_bounds__(256) void k_pass2(u16* __restrict__ S1b, u16* __restrict__ S2b,
                                               float* __restrict__ z1, float* __restrict__ z2,
                                               const float* __restrict__ P1, const float* __restrict__ P2) {
    int blk = blockIdx.x;
    if (blk < 512) {
        int bh = blk >> 4;
        int e = ((blk & 15) << 8) + threadIdx.x;
        float c1 = 0.f, c2 = 0.f;
        #pragma unroll 4
        for (int c = 0; c < NCH; c++) {
            int bc = bh * NCH + c;
            size_t idx = (size_t)bc * 4096 + e;
            float p1 = P1[bc], p2 = P2[bc];
            float t1 = b2f(S1b[idx]); S1b[idx] = f2b(c1); c1 = c1 * p1 + t1;
            float t2 = b2f(S2b[idx]); S2b[idx] = f2b(c2); c2 = c2 * p2 + t2;
        }
    } else {
        int bh = ((blk - 512) << 2) + (threadIdx.x >> 6);
        int e = threadIdx.x & 63;
        float y1 = 0.f, y2 = 0.f;
        #pragma unroll 4
        for (int c = 0; c < NCH; c++) {
            int bc = bh * NCH + c;
            size_t zi = (size_t)bc * 64 + e;
            float p1 = P1[bc], p2 = P2[bc];
            float t1 = z1[zi]; z1[zi] = y1; y1 = y1 * p1 + t1;
            float t2 = z2[zi]; z2[zi] = y2; y2 = y2 * p2 + t2;
        }
    }
}

// ---------------- pass3 (MFMA): per-chunk outputs; H frags direct from global ---------
__global__ __launch_bounds__(256) void k_pass3(const u16* __restrict__ qh, const u16* __restrict__ kh,
                                               const u16* __restrict__ vh, const float* __restrict__ lb1,
                                               const float* __restrict__ lb2, const u16* __restrict__ S1b,
                                               const u16* __restrict__ S2b, const float* __restrict__ z1,
                                               const float* __restrict__ z2, const float* __restrict__ mask,
                                               u16* __restrict__ obf) {
    __shared__ u16 Vt[64 * 72];
    __shared__ u16 AWs[64 * 72];
    __shared__ float Ls1[64], Ls2[64], dens[64], qZ1[64], qZ2[64];
    int tid = threadIdx.x;
    int bh = blockIdx.x >> 5, c = blockIdx.x & 31;
    int wave = tid >> 6, lane = tid & 63;
    size_t base = ((size_t)bh * S_ + c * CL) * DH;
    if (wave == 0) {
        float v = lb1[(size_t)bh * S_ + c * CL + lane];
        #pragma unroll
        for (int d = 1; d < 64; d <<= 1) { float o = __shfl_up(v, d, 64); if (lane >= d) v += o; }
        Ls1[lane] = v;
    } else if (wave == 1) {
        float v = lb2[(size_t)bh * S_ + c * CL + lane];
        #pragma unroll
        for (int d = 1; d < 64; d <<= 1) { float o = __shfl_up(v, d, 64); if (lane >= d) v += o; }
        Ls2[lane] = v;
    }
    {
        int ss = tid & 63, i0 = (tid >> 6) << 4;
        const u16* vr = vh + base + (size_t)ss * DH + i0;
        u16x8 vv0 = *(const u16x8*)vr;
        u16x8 vv1 = *(const u16x8*)(vr + 8);
        #pragma unroll
        for (int j = 0; j < 8; j++) {
            Vt[SW(i0 + j, ss)] = vv0[j];
            Vt[SW(i0 + 8 + j, ss)] = vv1[j];
        }
    }
    {
        int t = tid >> 2, g = tid & 3;
        const u16* qp = qh + base + (size_t)t * DH + (g << 4);
        u16x8 q0 = *(const u16x8*)qp;
        u16x8 q1 = *(const u16x8*)(qp + 8);
        const float* z1p = z1 + (size_t)blockIdx.x * 64 + (g << 4);
        const float* z2p = z2 + (size_t)blockIdx.x * 64 + (g << 4);
        float az1 = 0.f, az2 = 0.f;
        #pragma unroll
        for (int m = 0; m < 8; m++) {
            float qv0 = b2f(q0[m]), qv1 = b2f(q1[m]);
            az1 += qv0 * z1p[m] + qv1 * z1p[m + 8];
            az2 += qv0 * z2p[m] + qv1 * z2p[m + 8];
        }
        az1 += __shfl_xor(az1, 1, 64); az1 += __shfl_xor(az1, 2, 64);
        az2 += __shfl_xor(az2, 1, 64); az2 += __shfl_xor(az2, 2, 64);
        if (g == 0) { qZ1[t] = az1; qZ2[t] = az2; }
    }
    int l15 = lane & 15, kh8 = (lane >> 4) << 3;
    int t0 = wave << 4;
    const u16* qb = qh + base + (size_t)(t0 + l15) * DH;
    bf16x8 qf0 = *(const bf16x8*)(qb + kh8);
    bf16x8 qf1 = *(const bf16x8*)(qb + 32 + kh8);
    f32x4 accA[4];
    #pragma unroll
    for (int st = 0; st < 4; st++) accA[st] = (f32x4){0, 0, 0, 0};
    #pragma unroll
    for (int st = 0; st < 4; st++) {
        const u16* kb = kh + base + (size_t)((st << 4) + l15) * DH;
        bf16x8 kf0 = *(const bf16x8*)(kb + kh8);
        bf16x8 kf1 = *(const bf16x8*)(kb + 32 + kh8);
        accA[st] = __builtin_amdgcn_mfma_f32_16x16x32_bf16(qf0, kf0, accA[st], 0, 0, 0);
        accA[st] = __builtin_amdgcn_mfma_f32_16x16x32_bf16(qf1, kf1, accA[st], 0, 0, 0);
    }
    __syncthreads();
    int trow = t0 + ((lane >> 4) << 2);
    float l1t[4], l2t[4];
    #pragma unroll
    for (int r = 0; r < 4; r++) { l1t[r] = Ls1[trow + r]; l2t[r] = Ls2[trow + r]; }
    float rs[4] = {0.f, 0.f, 0.f, 0.f};
    #pragma unroll
    for (int st = 0; st < 4; st++) {
        int s = (st << 4) + l15;
        float s1 = Ls1[s], s2 = Ls2[s];
        #pragma unroll
        for (int r = 0; r < 4; r++) {
            float w = 0.f;
            if (s <= trow + r) w = exp2f(l1t[r] - s1) + exp2f(l2t[r] - s2);
            u16 awb = f2b(accA[st][r] * w);
            AWs[SW(trow + r, s)] = awb;
            rs[r] += b2f(awb);
        }
    }
    #pragma unroll
    for (int off = 1; off < 16; off <<= 1) {
        #pragma unroll
        for (int r = 0; r < 4; r++) rs[r] += __shfl_xor(rs[r], off, 64);
    }
    if (l15 == 0) {
        #pragma unroll
        for (int r = 0; r < 4; r++) dens[trow + r] = rs[r];
    }
    __syncthreads();
    bf16x8 awf0 = *(const bf16x8*)&AWs[SW(t0 + l15, kh8)];
    bf16x8 awf1 = *(const bf16x8*)&AWs[SW(t0 + l15, 32 + kh8)];
    const u16* h1g = S1b + (size_t)blockIdx.x * 4096;
    const u16* h2g = S2b + (size_t)blockIdx.x * 4096;
    f32x4 accO[4], accC1[4], accC2[4];
    #pragma unroll
    for (int jt = 0; jt < 4; jt++) {
        accO[jt] = (f32x4){0, 0, 0, 0};
        accC1[jt] = (f32x4){0, 0, 0, 0};
        accC2[jt] = (f32x4){0, 0, 0, 0};
    }
    #pragma unroll
    for (int jt = 0; jt < 4; jt++) {
        int jr = (jt << 4) + l15;
        bf16x8 v0 = *(const bf16x8*)&Vt[SW(jr, kh8)];
        bf16x8 v1 = *(const bf16x8*)&Vt[SW(jr, 32 + kh8)];
        accO[jt] = __builtin_amdgcn_mfma_f32_16x16x32_bf16(awf0, v0, accO[jt], 0, 0, 0);
        accO[jt] = __builtin_amdgcn_mfma_f32_16x16x32_bf16(awf1, v1, accO[jt], 0, 0, 0);
        bf16x8 h10 = *(const bf16x8*)(h1g + (size_t)jr * 64 + kh8);
        bf16x8 h11 = *(const bf16x8*)(h1g + (size_t)jr * 64 + 32 + kh8);
        accC1[jt] = __builtin_amdgcn_mfma_f32_16x16x32_bf16(qf0, h10, accC1[jt], 0, 0, 0);
        accC1[jt] = __builtin_amdgcn_mfma_f32_16x16x32_bf16(qf1, h11, accC1[jt], 0, 0, 0);
        bf16x8 h20 = *(const bf16x8*)(h2g + (size_t)jr * 64 + kh8);
        bf16x8 h21 = *(const bf16x8*)(h2g + (size_t)jr * 64 + 32 + kh8);
        accC2[jt] = __builtin_amdgcn_mfma_f32_16x16x32_bf16(qf0, h20, accC2[jt], 0, 0, 0);
        accC2[jt] = __builtin_amdgcn_mfma_f32_16x16x32_bf16(qf1, h21, accC2[jt], 0, 0, 0);
    }
    int b = bh >> 3, hh = bh & 7;
    #pragma unroll
    for (int r = 0; r < 4; r++) {
        int t = trow + r;
        float e1 = exp2f(l1t[r]), e2 = exp2f(l2t[r]);
        float den = dens[t] + e1 * qZ1[t] + e2 * qZ2[t];
        den = fmaxf(den, 1e-6f);
        int sg = (c << 6) + t;
        float mv = mask[(size_t)b * S_ + sg];
        float inv = mv / den;
        u16* op = obf + ((size_t)b * S_ + sg) * DM + hh * DH;
        #pragma unroll
        for (int jt = 0; jt < 4; jt++) {
            float numv = accO[jt][r] + e1 * accC1[jt][r] + e2 * accC2[jt][r];
            op[(jt << 4) + l15] = f2b(numv * inv);
        }
    }
}

extern "C" void kernel_launch(void* const* d_in, const int* in_sizes, int n_in,
                              void* d_out, int out_size, void* d_ws, size_t ws_size,
                              hipStream_t stream) {
    const float* x    = (const float*)d_in[0];
    const float* mask = (const float*)d_in[1];
    const float* Wq   = (const float*)d_in[2];
    const float* Wk   = (const float*)d_in[3];
    const float* Wv   = (const float*)d_in[4];
    const float* Wb   = (const float*)d_in[5];
    const float* bb   = (const float*)d_in[6];
    const float* Wo   = (const float*)d_in[7];
    const float* bo   = (const float*)d_in[8];
    const float* lnw  = (const float*)d_in[9];
    const float* rec  = (const float*)d_in[10];
    const float* bb1  = (const float*)d_in[11];
    const float* bb2  = (const float*)d_in[12];
    float* out = (float*)d_out;

    char* w = (char*)d_ws;
    u16* h    = (u16*)w;  w += (size_t)8192 * 512 * 2;
    u16* wcat = (u16*)w;  w += (size_t)1536 * 512 * 2;
    u16* wo   = (u16*)w;  w += (size_t)512 * 512 * 2;
    u16* qh   = (u16*)w;  w += (size_t)8192 * 512 * 2;
    u16* kh   = (u16*)w;  w += (size_t)8192 * 512 * 2;
    u16* vh   = (u16*)w;  w += (size_t)8192 * 512 * 2;
    float* lb1 = (float*)w; w += (size_t)32 * 2048 * 4;
    float* lb2 = (float*)w; w += (size_t)32 * 2048 * 4;
    u16* S1b  = (u16*)w;  w += (size_t)1024 * 4096 * 2;
    u16* S2b  = (u16*)w;  w += (size_t)1024 * 4096 * 2;
    float* z1  = (float*)w; w += (size_t)1024 * 64 * 4;
    float* z2  = (float*)w; w += (size_t)1024 * 64 * 4;
    float* P1  = (float*)w; w += 4096;
    float* P2  = (float*)w; w += 4096;
    u16* obf   = (u16*)w;   w += (size_t)8192 * 512 * 2;

    k_rbw<<<3072, 256, 0, stream>>>(x, lnw, Wb, bb, rec, bb1, bb2, h, lb1, lb2,
                                    Wq, Wk, Wv, Wo, wcat, wo);
    k_gemm<0, 12><<<dim3(64, 12), 256, 0, stream>>>(h, wcat, 512, mask, qh, kh, vh, nullptr, nullptr, nullptr);
    k_pass1<<<1024, 256, 0, stream>>>(kh, vh, lb1, lb2, S1b, S2b, z1, z2, P1, P2);
    k_pass2<<<520, 256, 0, stream>>>(S1b, S2b, z1, z2, P1, P2);
    k_pass3<<<1024, 256, 0, stream>>>(qh, kh, vh, lb1, lb2, S1b, S2b, z1, z2, mask, obf);
    k_gemm<1, 4><<<dim3(64, 4), 256, 0, stream>>>(obf, wo, 512, nullptr, nullptr, nullptr, nullptr, x, bo, out);
}

// Round 7
// 99.592 us; speedup vs baseline: 1.6787x; 1.0539x over previous
//
#include <hip/hip_runtime.h>
#include <stdint.h>

typedef unsigned short u16;
typedef short bf16x8 __attribute__((ext_vector_type(8)));
typedef unsigned short u16x8 __attribute__((ext_vector_type(8)));
typedef unsigned short u16x4 __attribute__((ext_vector_type(4)));
typedef float f32x4 __attribute__((ext_vector_type(4)));

#define S_ 2048
#define DM 512
#define DH 64
#define CL 64
#define NCH 32

// swizzled LDS index (u16 elems): row stride 72, XOR col bits 3..5 with row&7
#define SW(r, sc) ((r) * 72 + ((sc) ^ (((r) & 7) << 3)))

__device__ __forceinline__ float b2f(u16 u) { return __uint_as_float(((unsigned)u) << 16); }
__device__ __forceinline__ u16 f2b(float f) {
    unsigned v = __float_as_uint(f);
    unsigned r = v + 0x7fffu + ((v >> 16) & 1u);
    return (u16)(r >> 16);
}
__device__ __forceinline__ float phi_elu(float x) { return x > 0.f ? x + 1.f : __expf(x); }
__device__ __forceinline__ float clip01(float v) { return fminf(fmaxf(v, 0.01f), 0.995f); }

__device__ __forceinline__ void gload16(const u16* g, u16* l) {
    __builtin_amdgcn_global_load_lds((const __attribute__((address_space(1))) void*)g,
                                     (__attribute__((address_space(3))) void*)l, 16, 0, 0);
}

// ---------------- fused RMSNorm+beta (blocks 0..2047) and weight-convert (2048..3071) --
__global__ __launch_bounds__(256) void k_rbw(const float* __restrict__ x, const float* __restrict__ lnw,
                                             const float* __restrict__ Wb, const float* __restrict__ bb,
                                             const float* __restrict__ rec, const float* __restrict__ bb1p,
                                             const float* __restrict__ bb2p, u16* __restrict__ h,
                                             float* __restrict__ lb1, float* __restrict__ lb2,
                                             const float* __restrict__ Wq, const float* __restrict__ Wk,
                                             const float* __restrict__ Wv, const float* __restrict__ Wo,
                                             u16* __restrict__ wcat, u16* __restrict__ wo) {
    if (blockIdx.x >= 2048) {
        int idx = (blockIdx.x - 2048) * 256 + threadIdx.x;
        int e0 = idx << 2;
        if (e0 < 1536 * 512) {
            int r = e0 >> 9, ccol = e0 & 511;
            const float* src = (r < 512) ? (Wq + (size_t)r * 512)
                             : (r < 1024) ? (Wk + (size_t)(r - 512) * 512)
                                          : (Wv + (size_t)(r - 1024) * 512);
            float4 v = *(const float4*)(src + ccol);
            u16x4 o = {f2b(v.x), f2b(v.y), f2b(v.z), f2b(v.w)};
            *(u16x4*)(wcat + e0) = o;
        } else {
            int e = e0 - 1536 * 512;
            float4 v = *(const float4*)(Wo + e);
            u16x4 o = {f2b(v.x), f2b(v.y), f2b(v.z), f2b(v.w)};
            *(u16x4*)(wo + e) = o;
        }
        return;
    }
    int wave = threadIdx.x >> 6, lane = threadIdx.x & 63;
    int row = blockIdx.x * 4 + wave;
    const float* xr = x + (size_t)row * DM + lane * 8;
    float4 v0 = *(const float4*)xr;
    float4 v1 = *(const float4*)(xr + 4);
    float ss = v0.x * v0.x + v0.y * v0.y + v0.z * v0.z + v0.w * v0.w +
               v1.x * v1.x + v1.y * v1.y + v1.z * v1.z + v1.w * v1.w;
    #pragma unroll
    for (int off = 32; off; off >>= 1) ss += __shfl_xor(ss, off, 64);
    float sc = rsqrtf(ss * (1.f / DM) + 1e-5f);
    const float* wr_ = lnw + lane * 8;
    float4 w0 = *(const float4*)wr_;
    float4 w1 = *(const float4*)(wr_ + 4);
    float hv[8];
    hv[0] = v0.x * sc * w0.x; hv[1] = v0.y * sc * w0.y;
    hv[2] = v0.z * sc * w0.z; hv[3] = v0.w * sc * w0.w;
    hv[4] = v1.x * sc * w1.x; hv[5] = v1.y * sc * w1.y;
    hv[6] = v1.z * sc * w1.z; hv[7] = v1.w * sc * w1.w;
    u16x8 o;
    #pragma unroll
    for (int j = 0; j < 8; j++) o[j] = f2b(hv[j]);
    *(u16x8*)(h + (size_t)row * DM + lane * 8) = o;
    float acc[8];
    #pragma unroll
    for (int hd = 0; hd < 8; hd++) {
        const float* wp = Wb + hd * DM + lane * 8;
        float4 a0 = *(const float4*)wp;
        float4 a1 = *(const float4*)(wp + 4);
        acc[hd] = hv[0] * a0.x + hv[1] * a0.y + hv[2] * a0.z + hv[3] * a0.w +
                  hv[4] * a1.x + hv[5] * a1.y + hv[6] * a1.z + hv[7] * a1.w;
    }
    #pragma unroll
    for (int hd = 0; hd < 8; hd++) {
        #pragma unroll
        for (int off = 32; off; off >>= 1) acc[hd] += __shfl_xor(acc[hd], off, 64);
    }
    if (lane == 0) {
        float b1b = clip01(1.f / (1.f + __expf(-bb1p[0])));
        float b2b = clip01(1.f / (1.f + __expf(-bb2p[0])));
        int b = row >> 11, s = row & 2047;
        #pragma unroll
        for (int hd = 0; hd < 8; hd++) {
            float logit = acc[hd] + bb[hd] + rec[hd];
            float beta = 1.f / (1.f + __expf(-logit));
            float bin = clip01(beta);
            float b1 = clip01(b1b * bin);
            float b2 = clip01(b2b * bin);
            size_t o2 = (size_t)((b << 3) + hd) * S_ + s;
            lb1[o2] = log2f(b1);
            lb2[o2] = log2f(b2);
        }
    }
}

// ---------------- MFMA bf16 GEMM: BK=64, XOR-swizzled LDS, XCD swizzle, LDS-bounce ----
// LDS[row][colg] = global[row][colg ^ (row&7)] (8-elem granules); read at kg^(row&7).
template<int MODE, int NT>
__global__ __launch_bounds__(256) void k_gemm(const u16* __restrict__ A, const u16* __restrict__ Bw, int K,
                                              const float* __restrict__ mask, u16* __restrict__ qh,
                                              u16* __restrict__ kh, u16* __restrict__ vh,
                                              const float* __restrict__ xres, const float* __restrict__ bo,
                                              float* __restrict__ outp) {
    __shared__ u16 SH[16384];   // As [0,8192), Bs [8192,16384); epilogue bounce aliases
    u16* As = SH;
    u16* Bs = SH + 8192;
    int tid = threadIdx.x;
    int lane = tid & 63, w = tid >> 6;
    int wr = w >> 1, wc = w & 1;
    int hwid = blockIdx.y * gridDim.x + blockIdx.x;
    int nwg = gridDim.x * NT;
    int q8 = nwg >> 3;
    int logical = (hwid & 7) * q8 + (hwid >> 3);
    int mTile = logical / NT, nTile = logical % NT;
    int m0 = mTile * 128, n0 = nTile * 128;
    f32x4 acc[4][4] = {};
    int r0 = tid >> 3;
    int swc8 = ((lane & 7) ^ (lane >> 3)) << 3;
    const u16* gA0 = A + (size_t)(m0 + r0) * K + swc8;
    const u16* gB0 = Bw + (size_t)(n0 + r0) * K + swc8;
    u16* lA = As + w * 512;
    u16* lB = Bs + w * 512;
    int l15 = lane & 15;
    int kgrp = lane >> 4;
    for (int k0 = 0; k0 < K; k0 += 64) {
        if (k0) __syncthreads();
        #pragma unroll
        for (int rb = 0; rb < 4; rb++) {
            gload16(gA0 + (size_t)rb * 32 * K + k0, lA + rb * 2048);
            gload16(gB0 + (size_t)rb * 32 * K + k0, lB + rb * 2048);
        }
        __syncthreads();
        #pragma unroll
        for (int kk = 0; kk < 2; kk++) {
            int kg = kgrp + kk * 4;
            int cg = (kg ^ (l15 & 7)) << 3;
            bf16x8 af[4], bfr[4];
            #pragma unroll
            for (int m = 0; m < 4; m++) af[m] = *(const bf16x8*)&As[(wr * 64 + m * 16 + l15) * 64 + cg];
            #pragma unroll
            for (int n = 0; n < 4; n++) bfr[n] = *(const bf16x8*)&Bs[(wc * 64 + n * 16 + l15) * 64 + cg];
            #pragma unroll
            for (int m = 0; m < 4; m++)
                #pragma unroll
                for (int n = 0; n < 4; n++)
                    acc[m][n] = __builtin_amdgcn_mfma_f32_16x16x32_bf16(af[m], bfr[n], acc[m][n], 0, 0, 0);
        }
    }
    __syncthreads();   // staging dead; reuse SH for epilogue bounce
    if constexpr (MODE == 0) {
        int mat = n0 >> 9;
        int cb = n0 & 511;
        u16* basep = (mat == 0) ? qh : (mat == 1) ? kh : vh;
        #pragma unroll
        for (int P = 0; P < 2; P++) {
            if (wr == P) {
                #pragma unroll
                for (int m = 0; m < 4; m++)
                    #pragma unroll
                    for (int n = 0; n < 4; n++)
                        #pragma unroll
                        for (int r = 0; r < 4; r++) {
                            int rl = m * 16 + ((lane >> 4) << 2) + r;
                            int colL = wc * 64 + n * 16 + l15;
                            SH[rl * 140 + colL] = f2b(acc[m][n][r]);
                        }
            }
            __syncthreads();
            {
                int rl = tid >> 2;
                int gr = m0 + P * 64 + rl;
                int b = gr >> 11, s = gr & 2047;
                float mv = (mat == 1) ? mask[(b << 11) + s] : 1.f;
                #pragma unroll
                for (int cc = 0; cc < 4; cc++) {
                    int cl = ((tid & 3) << 5) + (cc << 3);
                    u16x8 vv = *(const u16x8*)&SH[rl * 140 + cl];
                    int f = cb + cl;
                    int hh = f >> 6, j = f & 63;
                    u16* dst = basep + ((size_t)(b * 8 + hh) * S_ + s) * DH + j;
                    if (mat == 2) {
                        *(u16x8*)dst = vv;
                    } else {
                        u16x8 ov;
                        #pragma unroll
                        for (int e = 0; e < 8; e++) {
                            float v = b2f(vv[e]);
                            ov[e] = f2b(phi_elu(v) * mv);
                        }
                        *(u16x8*)dst = ov;
                    }
                }
            }
            __syncthreads();
        }
    } else {
        float* SF = (float*)SH;
        #pragma unroll
        for (int Pq = 0; Pq < 4; Pq++) {
            if (wr == (Pq >> 1)) {
                int mbase = (Pq & 1) * 2;
                #pragma unroll
                for (int mm = 0; mm < 2; mm++)
                    #pragma unroll
                    for (int n = 0; n < 4; n++)
                        #pragma unroll
                        for (int r = 0; r < 4; r++) {
                            int rl = mm * 16 + ((lane >> 4) << 2) + r;
                            int colL = wc * 64 + n * 16 + l15;
                            SF[rl * 136 + colL] = acc[mbase + mm][n][r];
                        }
            }
            __syncthreads();
            {
                int rl = tid >> 3;
                int gr = m0 + Pq * 32 + rl;
                int col0 = (tid & 7) << 4;
                const float* xr = xres + (size_t)gr * DM + n0 + col0;
                float* orow = outp + (size_t)gr * DM + n0 + col0;
                #pragma unroll
                for (int cc = 0; cc < 4; cc++) {
                    int cl = col0 + (cc << 2);
                    float4 v = *(const float4*)&SF[rl * 136 + cl];
                    float4 xv = *(const float4*)(xr + (cc << 2));
                    float4 bv = *(const float4*)(bo + n0 + cl);
                    float4 ov = {v.x + xv.x + bv.x, v.y + xv.y + bv.y,
                                 v.z + xv.z + bv.z, v.w + xv.w + bv.w};
                    *(float4*)(orow + (cc << 2)) = ov;
                }
            }
            __syncthreads();
        }
    }
}

// ---------------- pass1 (MFMA): per-chunk S1^T,S2^T (bf16), z1,z2, P1,P2 --------------
__global__ __launch_bounds__(256) void k_pass1(const u16* __restrict__ kh, const u16* __restrict__ vh,
                                               const float* __restrict__ lb1, const float* __restrict__ lb2,
                                               u16* __restrict__ S1b, u16* __restrict__ S2b,
                                               float* __restrict__ z1, float* __restrict__ z2,
                                               float* __restrict__ P1, float* __restrict__ P2) {
    __shared__ u16 Kw1[64 * 72];
    __shared__ u16 Kw2[64 * 72];
    __shared__ u16 Vt[64 * 72];
    __shared__ float Ls1[64], Ls2[64];
    int tid = threadIdx.x;
    int bh = blockIdx.x >> 5, c = blockIdx.x & 31;
    int wave = tid >> 6, lane = tid & 63;
    size_t base = ((size_t)bh * S_ + c * CL) * DH;
    if (wave == 0) {
        float v = lb1[(size_t)bh * S_ + c * CL + lane];
        #pragma unroll
        for (int d = 1; d < 64; d <<= 1) { float o = __shfl_up(v, d, 64); if (lane >= d) v += o; }
        Ls1[lane] = v;
    } else if (wave == 1) {
        float v = lb2[(size_t)bh * S_ + c * CL + lane];
        #pragma unroll
        for (int d = 1; d < 64; d <<= 1) { float o = __shfl_up(v, d, 64); if (lane >= d) v += o; }
        Ls2[lane] = v;
    }
    int ss = tid & 63, i0 = (tid >> 6) << 4;
    const u16* kr = kh + base + (size_t)ss * DH + i0;
    u16x8 kk0 = *(const u16x8*)kr;
    u16x8 kk1 = *(const u16x8*)(kr + 8);
    {
        const u16* vr = vh + base + (size_t)ss * DH + i0;
        u16x8 vv0 = *(const u16x8*)vr;
        u16x8 vv1 = *(const u16x8*)(vr + 8);
        #pragma unroll
        for (int j = 0; j < 8; j++) {
            Vt[SW(i0 + j, ss)] = vv0[j];
            Vt[SW(i0 + 8 + j, ss)] = vv1[j];
        }
    }
    __syncthreads();
    float w1 = exp2f(Ls1[63] - Ls1[ss]);
    float w2 = exp2f(Ls2[63] - Ls2[ss]);
    #pragma unroll
    for (int j = 0; j < 8; j++) {
        float k0 = b2f(kk0[j]), k1 = b2f(kk1[j]);
        Kw1[SW(i0 + j, ss)] = f2b(w1 * k0);
        Kw2[SW(i0 + j, ss)] = f2b(w2 * k0);
        Kw1[SW(i0 + 8 + j, ss)] = f2b(w1 * k1);
        Kw2[SW(i0 + 8 + j, ss)] = f2b(w2 * k1);
    }
    if (tid == 0) { P1[blockIdx.x] = exp2f(Ls1[63]); P2[blockIdx.x] = exp2f(Ls2[63]); }
    __syncthreads();
    int l15 = lane & 15, kh8 = (lane >> 4) << 3;
    int j0 = wave << 4;
    bf16x8 vf0 = *(const bf16x8*)&Vt[SW(j0 + l15, kh8)];
    bf16x8 vf1 = *(const bf16x8*)&Vt[SW(j0 + l15, 32 + kh8)];
    f32x4 a1[4], a2[4];
    #pragma unroll
    for (int it = 0; it < 4; it++) { a1[it] = (f32x4){0,0,0,0}; a2[it] = (f32x4){0,0,0,0}; }
    #pragma unroll
    for (int it = 0; it < 4; it++) {
        int ir = (it << 4) + l15;
        bf16x8 b0 = *(const bf16x8*)&Kw1[SW(ir, kh8)];
        bf16x8 b1 = *(const bf16x8*)&Kw1[SW(ir, 32 + kh8)];
        a1[it] = __builtin_amdgcn_mfma_f32_16x16x32_bf16(vf0, b0, a1[it], 0, 0, 0);
        a1[it] = __builtin_amdgcn_mfma_f32_16x16x32_bf16(vf1, b1, a1[it], 0, 0, 0);
        bf16x8 c0 = *(const bf16x8*)&Kw2[SW(ir, kh8)];
        bf16x8 c1 = *(const bf16x8*)&Kw2[SW(ir, 32 + kh8)];
        a2[it] = __builtin_amdgcn_mfma_f32_16x16x32_bf16(vf0, c0, a2[it], 0, 0, 0);
        a2[it] = __builtin_amdgcn_mfma_f32_16x16x32_bf16(vf1, c1, a2[it], 0, 0, 0);
    }
    {
        int iz = tid >> 2, sg = tid & 3;
        u16x8 x0 = *(const u16x8*)&Kw1[SW(iz, sg << 4)];
        u16x8 x1 = *(const u16x8*)&Kw1[SW(iz, (sg << 4) + 8)];
        u16x8 y0 = *(const u16x8*)&Kw2[SW(iz, sg << 4)];
        u16x8 y1 = *(const u16x8*)&Kw2[SW(iz, (sg << 4) + 8)];
        float z1v = 0.f, z2v = 0.f;
        #pragma unroll
        for (int j = 0; j < 8; j++) {
            z1v += b2f(x0[j]) + b2f(x1[j]);
            z2v += b2f(y0[j]) + b2f(y1[j]);
        }
        z1v += __shfl_xor(z1v, 1, 64); z1v += __shfl_xor(z1v, 2, 64);
        z2v += __shfl_xor(z2v, 1, 64); z2v += __shfl_xor(z2v, 2, 64);
        if (sg == 0) {
            z1[(size_t)blockIdx.x * 64 + iz] = z1v;
            z2[(size_t)blockIdx.x * 64 + iz] = z2v;
        }
    }
    int jr0 = j0 + ((lane >> 4) << 2);
    size_t so = (size_t)blockIdx.x * 4096;
    #pragma unroll
    for (int it = 0; it < 4; it++) {
        int ii = (it << 4) + l15;
        #pragma unroll
        for (int r = 0; r < 4; r++) {
            S1b[so + (size_t)(jr0 + r) * 64 + ii] = f2b(a1[it][r]);
            S2b[so + (size_t)(jr0 + r) * 64 + ii] = f2b(a2[it][r]);
        }
    }
}

// ---------------- pass2: cross-chunk scan, one thread per (bh, elem) ------------------
__global__ __launch_bounds__(256) void k_pass2(u16* __restrict__ S1b, u16* __restrict__ S2b,
                                               float* __restrict__ z1, float* __restrict__ z2,
                                               const float* __restrict__ P1, const float* __restrict__ P2) {
    int blk = blockIdx.x;
    if (blk < 512) {
        int bh = blk >> 4;
        int e = ((blk & 15) << 8) + threadIdx.x;
        float c1 = 0.f, c2 = 0.f;
        #pragma unroll 4
        for (int c = 0; c < NCH; c++) {
            int bc = bh * NCH + c;
            size_t idx = (size_t)bc * 4096 + e;
            float p1 = P1[bc], p2 = P2[bc];
            float t1 = b2f(S1b[idx]); S1b[idx] = f2b(c1); c1 = c1 * p1 + t1;
            float t2 = b2f(S2b[idx]); S2b[idx] = f2b(c2); c2 = c2 * p2 + t2;
        }
    } else {
        int bh = ((blk - 512) << 2) + (threadIdx.x >> 6);
        int e = threadIdx.x & 63;
        float y1 = 0.f, y2 = 0.f;
        #pragma unroll 4
        for (int c = 0; c < NCH; c++) {
            int bc = bh * NCH + c;
            size_t zi = (size_t)bc * 64 + e;
            float p1 = P1[bc], p2 = P2[bc];
            float t1 = z1[zi]; z1[zi] = y1; y1 = y1 * p1 + t1;
            float t2 = z2[zi]; z2[zi] = y2; y2 = y2 * p2 + t2;
        }
    }
}

// ---------------- pass3 (MFMA): per-chunk outputs; H frags direct from global ---------
__global__ __launch_bounds__(256) void k_pass3(const u16* __restrict__ qh, const u16* __restrict__ kh,
                                               const u16* __restrict__ vh, const float* __restrict__ lb1,
                                               const float* __restrict__ lb2, const u16* __restrict__ S1b,
                                               const u16* __restrict__ S2b, const float* __restrict__ z1,
                                               const float* __restrict__ z2, const float* __restrict__ mask,
                                               u16* __restrict__ obf) {
    __shared__ u16 Vt[64 * 72];
    __shared__ u16 AWs[64 * 72];
    __shared__ float Ls1[64], Ls2[64], dens[64], qZ1[64], qZ2[64];
    int tid = threadIdx.x;
    int bh = blockIdx.x >> 5, c = blockIdx.x & 31;
    int wave = tid >> 6, lane = tid & 63;
    size_t base = ((size_t)bh * S_ + c * CL) * DH;
    if (wave == 0) {
        float v = lb1[(size_t)bh * S_ + c * CL + lane];
        #pragma unroll
        for (int d = 1; d < 64; d <<= 1) { float o = __shfl_up(v, d, 64); if (lane >= d) v += o; }
        Ls1[lane] = v;
    } else if (wave == 1) {
        float v = lb2[(size_t)bh * S_ + c * CL + lane];
        #pragma unroll
        for (int d = 1; d < 64; d <<= 1) { float o = __shfl_up(v, d, 64); if (lane >= d) v += o; }
        Ls2[lane] = v;
    }
    {
        int ss = tid & 63, i0 = (tid >> 6) << 4;
        const u16* vr = vh + base + (size_t)ss * DH + i0;
        u16x8 vv0 = *(const u16x8*)vr;
        u16x8 vv1 = *(const u16x8*)(vr + 8);
        #pragma unroll
        for (int j = 0; j < 8; j++) {
            Vt[SW(i0 + j, ss)] = vv0[j];
            Vt[SW(i0 + 8 + j, ss)] = vv1[j];
        }
    }
    {
        int t = tid >> 2, g = tid & 3;
        const u16* qp = qh + base + (size_t)t * DH + (g << 4);
        u16x8 q0 = *(const u16x8*)qp;
        u16x8 q1 = *(const u16x8*)(qp + 8);
        const float* z1p = z1 + (size_t)blockIdx.x * 64 + (g << 4);
        const float* z2p = z2 + (size_t)blockIdx.x * 64 + (g << 4);
        float az1 = 0.f, az2 = 0.f;
        #pragma unroll
        for (int m = 0; m < 8; m++) {
            float qv0 = b2f(q0[m]), qv1 = b2f(q1[m]);
            az1 += qv0 * z1p[m] + qv1 * z1p[m + 8];
            az2 += qv0 * z2p[m] + qv1 * z2p[m + 8];
        }
        az1 += __shfl_xor(az1, 1, 64); az1 += __shfl_xor(az1, 2, 64);
        az2 += __shfl_xor(az2, 1, 64); az2 += __shfl_xor(az2, 2, 64);
        if (g == 0) { qZ1[t] = az1; qZ2[t] = az2; }
    }
    int l15 = lane & 15, kh8 = (lane >> 4) << 3;
    int t0 = wave << 4;
    const u16* qb = qh + base + (size_t)(t0 + l15) * DH;
    bf16x8 qf0 = *(const bf16x8*)(qb + kh8);
    bf16x8 qf1 = *(const bf16x8*)(qb + 32 + kh8);
    f32x4 accA[4];
    #pragma unroll
    for (int st = 0; st < 4; st++) accA[st] = (f32x4){0, 0, 0, 0};
    #pragma unroll
    for (int st = 0; st < 4; st++) {
        const u16* kb = kh + base + (size_t)((st << 4) + l15) * DH;
        bf16x8 kf0 = *(const bf16x8*)(kb + kh8);
        bf16x8 kf1 = *(const bf16x8*)(kb + 32 + kh8);
        accA[st] = __builtin_amdgcn_mfma_f32_16x16x32_bf16(qf0, kf0, accA[st], 0, 0, 0);
        accA[st] = __builtin_amdgcn_mfma_f32_16x16x32_bf16(qf1, kf1, accA[st], 0, 0, 0);
    }
    __syncthreads();
    int trow = t0 + ((lane >> 4) << 2);
    float l1t[4], l2t[4];
    #pragma unroll
    for (int r = 0; r < 4; r++) { l1t[r] = Ls1[trow + r]; l2t[r] = Ls2[trow + r]; }
    float rs[4] = {0.f, 0.f, 0.f, 0.f};
    #pragma unroll
    for (int st = 0; st < 4; st++) {
        int s = (st << 4) + l15;
        float s1 = Ls1[s], s2 = Ls2[s];
        #pragma unroll
        for (int r = 0; r < 4; r++) {
            float w = 0.f;
            if (s <= trow + r) w = exp2f(l1t[r] - s1) + exp2f(l2t[r] - s2);
            u16 awb = f2b(accA[st][r] * w);
            AWs[SW(trow + r, s)] = awb;
            rs[r] += b2f(awb);
        }
    }
    #pragma unroll
    for (int off = 1; off < 16; off <<= 1) {
        #pragma unroll
        for (int r = 0; r < 4; r++) rs[r] += __shfl_xor(rs[r], off, 64);
    }
    if (l15 == 0) {
        #pragma unroll
        for (int r = 0; r < 4; r++) dens[trow + r] = rs[r];
    }
    __syncthreads();
    bf16x8 awf0 = *(const bf16x8*)&AWs[SW(t0 + l15, kh8)];
    bf16x8 awf1 = *(const bf16x8*)&AWs[SW(t0 + l15, 32 + kh8)];
    const u16* h1g = S1b + (size_t)blockIdx.x * 4096;
    const u16* h2g = S2b + (size_t)blockIdx.x * 4096;
    f32x4 accO[4], accC1[4], accC2[4];
    #pragma unroll
    for (int jt = 0; jt < 4; jt++) {
        accO[jt] = (f32x4){0, 0, 0, 0};
        accC1[jt] = (f32x4){0, 0, 0, 0};
        accC2[jt] = (f32x4){0, 0, 0, 0};
    }
    #pragma unroll
    for (int jt = 0; jt < 4; jt++) {
        int jr = (jt << 4) + l15;
        bf16x8 v0 = *(const bf16x8*)&Vt[SW(jr, kh8)];
        bf16x8 v1 = *(const bf16x8*)&Vt[SW(jr, 32 + kh8)];
        accO[jt] = __builtin_amdgcn_mfma_f32_16x16x32_bf16(awf0, v0, accO[jt], 0, 0, 0);
        accO[jt] = __builtin_amdgcn_mfma_f32_16x16x32_bf16(awf1, v1, accO[jt], 0, 0, 0);
        bf16x8 h10 = *(const bf16x8*)(h1g + (size_t)jr * 64 + kh8);
        bf16x8 h11 = *(const bf16x8*)(h1g + (size_t)jr * 64 + 32 + kh8);
        accC1[jt] = __builtin_amdgcn_mfma_f32_16x16x32_bf16(qf0, h10, accC1[jt], 0, 0, 0);
        accC1[jt] = __builtin_amdgcn_mfma_f32_16x16x32_bf16(qf1, h11, accC1[jt], 0, 0, 0);
        bf16x8 h20 = *(const bf16x8*)(h2g + (size_t)jr * 64 + kh8);
        bf16x8 h21 = *(const bf16x8*)(h2g + (size_t)jr * 64 + 32 + kh8);
        accC2[jt] = __builtin_amdgcn_mfma_f32_16x16x32_bf16(qf0, h20, accC2[jt], 0, 0, 0);
        accC2[jt] = __builtin_amdgcn_mfma_f32_16x16x32_bf16(qf1, h21, accC2[jt], 0, 0, 0);
    }
    int b = bh >> 3, hh = bh & 7;
    #pragma unroll
    for (int r = 0; r < 4; r++) {
        int t = trow + r;
        float e1 = exp2f(l1t[r]), e2 = exp2f(l2t[r]);
        float den = dens[t] + e1 * qZ1[t] + e2 * qZ2[t];
        den = fmaxf(den, 1e-6f);
        int sg = (c << 6) + t;
        float mv = mask[(size_t)b * S_ + sg];
        float inv = mv / den;
        u16* op = obf + ((size_t)b * S_ + sg) * DM + hh * DH;
        #pragma unroll
        for (int jt = 0; jt < 4; jt++) {
            float numv = accO[jt][r] + e1 * accC1[jt][r] + e2 * accC2[jt][r];
            op[(jt << 4) + l15] = f2b(numv * inv);
        }
    }
}

extern "C" void kernel_launch(void* const* d_in, const int* in_sizes, int n_in,
                              void* d_out, int out_size, void* d_ws, size_t ws_size,
                              hipStream_t stream) {
    const float* x    = (const float*)d_in[0];
    const float* mask = (const float*)d_in[1];
    const float* Wq   = (const float*)d_in[2];
    const float* Wk   = (const float*)d_in[3];
    const float* Wv   = (const float*)d_in[4];
    const float* Wb   = (const float*)d_in[5];
    const float* bb   = (const float*)d_in[6];
    const float* Wo   = (const float*)d_in[7];
    const float* bo   = (const float*)d_in[8];
    const float* lnw  = (const float*)d_in[9];
    const float* rec  = (const float*)d_in[10];
    const float* bb1  = (const float*)d_in[11];
    const float* bb2  = (const float*)d_in[12];
    float* out = (float*)d_out;

    char* w = (char*)d_ws;
    u16* h    = (u16*)w;  w += (size_t)8192 * 512 * 2;
    u16* wcat = (u16*)w;  w += (size_t)1536 * 512 * 2;
    u16* wo   = (u16*)w;  w += (size_t)512 * 512 * 2;
    u16* qh   = (u16*)w;  w += (size_t)8192 * 512 * 2;
    u16* kh   = (u16*)w;  w += (size_t)8192 * 512 * 2;
    u16* vh   = (u16*)w;  w += (size_t)8192 * 512 * 2;
    float* lb1 = (float*)w; w += (size_t)32 * 2048 * 4;
    float* lb2 = (float*)w; w += (size_t)32 * 2048 * 4;
    u16* S1b  = (u16*)w;  w += (size_t)1024 * 4096 * 2;
    u16* S2b  = (u16*)w;  w += (size_t)1024 * 4096 * 2;
    float* z1  = (float*)w; w += (size_t)1024 * 64 * 4;
    float* z2  = (float*)w; w += (size_t)1024 * 64 * 4;
    float* P1  = (float*)w; w += 4096;
    float* P2  = (float*)w; w += 4096;
    u16* obf   = (u16*)w;   w += (size_t)8192 * 512 * 2;

    k_rbw<<<3072, 256, 0, stream>>>(x, lnw, Wb, bb, rec, bb1, bb2, h, lb1, lb2,
                                    Wq, Wk, Wv, Wo, wcat, wo);
    k_gemm<0, 12><<<dim3(64, 12), 256, 0, stream>>>(h, wcat, 512, mask, qh, kh, vh, nullptr, nullptr, nullptr);
    k_pass1<<<1024, 256, 0, stream>>>(kh, vh, lb1, lb2, S1b, S2b, z1, z2, P1, P2);
    k_pass2<<<520, 256, 0, stream>>>(S1b, S2b, z1, z2, P1, P2);
    k_pass3<<<1024, 256, 0, stream>>>(qh, kh, vh, lb1, lb2, S1b, S2b, z1, z2, mask, obf);
    k_gemm<1, 4><<<dim3(64, 4), 256, 0, stream>>>(obf, wo, 512, nullptr, nullptr, nullptr, nullptr, x, bo, out);
}